// Round 1
// baseline (560.205 us; speedup 1.0000x reference)
//
#include <hip/hip_runtime.h>
#include <stdint.h>

#define S_LEN 2048
#define BATCH 2
#define NH 32
#define NKV 8
#define HD 128
#define NE 6144   // extracted columns of zxbcdt: x(1024) | B(1024) | C(4096)

typedef __attribute__((ext_vector_type(8))) short short8;
typedef __attribute__((ext_vector_type(4))) float floatx4;

__device__ __forceinline__ unsigned short f2bf(float f) {
    union { float f; uint32_t u; } v; v.f = f;
    uint32_t u = v.u;
    u += 0x7FFFu + ((u >> 16) & 1u);   // RTN-even (inputs are finite)
    return (unsigned short)(u >> 16);
}
__device__ __forceinline__ float bf2f(unsigned short h) {
    union { uint32_t u; float f; } v; v.u = ((uint32_t)h) << 16;
    return v.f;
}

// ---------------- cast fp32 -> bf16, 4 elems/thread ----------------
__global__ void cast_f32_bf16(const float* __restrict__ in,
                              unsigned short* __restrict__ out, int n4) {
    int i = blockIdx.x * blockDim.x + threadIdx.x;
    if (i >= n4) return;
    float4 f = reinterpret_cast<const float4*>(in)[i];
    ushort4 o;
    o.x = f2bf(f.x); o.y = f2bf(f.y); o.z = f2bf(f.z); o.w = f2bf(f.w);
    reinterpret_cast<ushort4*>(out)[i] = o;
}

// ---------------- m97-style B^T GEMM: C[M,N] = A[M,K] * Bt[N,K]^T ----------------
template <int OUT_BF16>
__global__ void __launch_bounds__(256)
gemm_bt(const unsigned short* __restrict__ A, const unsigned short* __restrict__ Bt,
        void* __restrict__ Cv, int M, int N, int K) {
    __shared__ unsigned short As[128 * 32];
    __shared__ unsigned short Bs[128 * 32];
    const int tid  = threadIdx.x;
    const int w    = tid >> 6;
    const int lane = tid & 63;
    const int quad = lane >> 4;
    const int l16  = lane & 15;
    const int wm   = w >> 1, wn = w & 1;
    const int m0 = blockIdx.y * 128, n0 = blockIdx.x * 128;

    floatx4 acc[4][4];
#pragma unroll
    for (int i = 0; i < 4; i++)
#pragma unroll
        for (int j = 0; j < 4; j++) acc[i][j] = {0.f, 0.f, 0.f, 0.f};

    const int lr = lane >> 2;        // row within 16-row chunk
    const int lk = (lane & 3) * 8;   // k-elem offset within 32
    const int KT = K >> 5;

    for (int kt = 0; kt < KT; ++kt) {
        const int k0 = kt << 5;
        __syncthreads();
#pragma unroll
        for (int c = 0; c < 2; ++c) {
            const int chunk = w * 2 + c;  // wave-uniform
            const unsigned short* ga = A  + (size_t)(m0 + chunk * 16 + lr) * K + k0 + lk;
            __builtin_amdgcn_global_load_lds(
                (const __attribute__((address_space(1))) void*)ga,
                (__attribute__((address_space(3))) void*)(As + chunk * 512), 16, 0, 0);
            const unsigned short* gb = Bt + (size_t)(n0 + chunk * 16 + lr) * K + k0 + lk;
            __builtin_amdgcn_global_load_lds(
                (const __attribute__((address_space(1))) void*)gb,
                (__attribute__((address_space(3))) void*)(Bs + chunk * 512), 16, 0, 0);
        }
        __syncthreads();
        short8 af[4], bf[4];
#pragma unroll
        for (int t = 0; t < 4; ++t) {
            af[t] = *reinterpret_cast<const short8*>(As + (wm * 64 + t * 16 + l16) * 32 + quad * 8);
            bf[t] = *reinterpret_cast<const short8*>(Bs + (wn * 64 + t * 16 + l16) * 32 + quad * 8);
        }
#pragma unroll
        for (int i = 0; i < 4; i++)
#pragma unroll
            for (int j = 0; j < 4; j++)
                acc[i][j] = __builtin_amdgcn_mfma_f32_16x16x32_bf16(af[i], bf[j], acc[i][j], 0, 0, 0);
    }

#pragma unroll
    for (int i = 0; i < 4; i++)
#pragma unroll
        for (int j = 0; j < 4; j++) {
            const int row = m0 + wm * 64 + i * 16 + quad * 4;
            const int col = n0 + wn * 64 + j * 16 + l16;
#pragma unroll
            for (int r = 0; r < 4; r++) {
                float vv = acc[i][j][r];
                if (OUT_BF16)
                    ((unsigned short*)Cv)[(size_t)(row + r) * N + col] = f2bf(vv);
                else
                    ((float*)Cv)[(size_t)(row + r) * N + col] = vv;
            }
        }
}

// ---------------- RoPE + split/reshape ----------------
// Z: [4096 tokens][6144] bf16. Q[B,NH,S,HD] (pre-scaled by log2e/sqrt(128)),
// K[B,NKV,S,HD], Vt[B,NKV,HD,S].
#define QSCALE 0.12748539509360f   // log2(e) / sqrt(128)
__global__ void rope_split(const unsigned short* __restrict__ Z,
                           unsigned short* __restrict__ Q,
                           unsigned short* __restrict__ Kb,
                           unsigned short* __restrict__ Vt) {
    const int PER_TOK = 2048 + 512 + 1024;  // q-pairs + k-pairs + v-elems
    int idx = blockIdx.x * blockDim.x + threadIdx.x;
    if (idx >= BATCH * S_LEN * PER_TOK) return;
    int t = idx / PER_TOK;
    int r = idx - t * PER_TOK;
    int b = t / S_LEN, s = t - b * S_LEN;
    const unsigned short* z = Z + (size_t)t * NE;
    if (r < 2048) {                 // q pair: C section
        int h = r >> 6, j = r & 63;
        float x0 = bf2f(z[2048 + h * 128 + j]);
        float x1 = bf2f(z[2048 + h * 128 + j + 64]);
        float inv = exp2f((float)j * -0.20762050593f);   // 10000^(-j/64)
        float c, sn; sincosf((float)s * inv, &sn, &c);
        size_t base = ((size_t)(b * NH + h) * S_LEN + s) * HD;
        Q[base + j]      = f2bf((x0 * c - x1 * sn) * QSCALE);
        Q[base + j + 64] = f2bf((x1 * c + x0 * sn) * QSCALE);
    } else if (r < 2560) {          // k pair: B section
        int rr = r - 2048; int kh = rr >> 6, j = rr & 63;
        float x0 = bf2f(z[1024 + kh * 128 + j]);
        float x1 = bf2f(z[1024 + kh * 128 + j + 64]);
        float inv = exp2f((float)j * -0.20762050593f);
        float c, sn; sincosf((float)s * inv, &sn, &c);
        size_t base = ((size_t)(b * NKV + kh) * S_LEN + s) * HD;
        Kb[base + j]      = f2bf(x0 * c - x1 * sn);
        Kb[base + j + 64] = f2bf(x1 * c + x0 * sn);
    } else {                        // v elem: x section, transposed store
        int m = r - 2560; int kh = m >> 7, d = m & 127;
        Vt[((size_t)(b * NKV + kh) * HD + d) * S_LEN + s] = z[m];
    }
}

// ---------------- Flash attention v2 (causal, GQA 4:1) ----------------
// Block = 4 waves, one (b,h,qt): 64 q rows. KV tiles of 64, DOUBLE-BUFFERED
// in LDS via T3 minimum-2-phase: issue next tile's global_load_lds BEFORE
// computing current tile; one raw s_barrier + vmcnt(0) per tile (raw barrier
// so the compiler's __syncthreads vmcnt-drain doesn't defeat the pipeline).
// K/V XOR chunk-swizzle chunk^(row&7) unchanged. P buffer: padded stride-72
// rows (144 B) instead of XOR swizzle -> all ds addresses fold to per-lane
// base + immediate offset (kills softmax address VALU).
// No online max: Q pre-scaled to log2 domain, p = exp2(t) directly.
__global__ void __launch_bounds__(256)
attn_kernel(const unsigned short* __restrict__ Q,
            const unsigned short* __restrict__ Kb,
            const unsigned short* __restrict__ Vt,
            unsigned short* __restrict__ Ob) {
    __shared__ unsigned short Ks[2][64 * 128];   // [s][d] swizzled, 2 x 16 KB
    __shared__ unsigned short Vs[2][64 * 128];   // [d][s] swizzled, 2 x 16 KB
    __shared__ unsigned short Ps[4][16 * 72];    // per-wave P, padded rows, 9 KB
    const int tid  = threadIdx.x;
    const int w    = tid >> 6;
    const int lane = tid & 63;
    const int quad = lane >> 4;
    const int l16  = lane & 15;
    const int blk = blockIdx.x;
    const int qt = 31 - (blk >> 6);      // heavy blocks dispatch first
    const int bh = blk & 63;
    const int h = bh & 31, b = bh >> 5;
    const int kvh = h >> 2;
    const int qw0 = qt * 64 + w * 16;

    const unsigned short* Qbase = Q  + ((size_t)(b * NH  + h)   * S_LEN) * HD;
    const unsigned short* Kbase = Kb + ((size_t)(b * NKV + kvh) * S_LEN) * HD;
    const unsigned short* Vbase = Vt + ((size_t)(b * NKV + kvh) * HD) * S_LEN;

    short8 qf[4];
    {
        const unsigned short* qrow = Qbase + (size_t)(qw0 + l16) * HD + quad * 8;
#pragma unroll
        for (int ks = 0; ks < 4; ++ks)
            qf[ks] = *reinterpret_cast<const short8*>(qrow + ks * 32);
    }

    floatx4 oacc[8];
#pragma unroll
    for (int i = 0; i < 8; i++) oacc[i] = {0.f, 0.f, 0.f, 0.f};
    float lsum[4] = {0.f, 0.f, 0.f, 0.f};

    // per-lane staging pointers, advanced by one KV tile per STAGE
    const unsigned short* kp[4];
    const unsigned short* vp[4];
#pragma unroll
    for (int c = 0; c < 4; ++c) {
        const int bI = w * 4 + c;                       // wave-uniform block idx
        const int krow = bI * 4 + (lane >> 4);          // 0..63
        kp[c] = Kbase + (size_t)krow * HD + ((lane & 15) ^ (krow & 7)) * 8;
        const int drow = bI * 8 + (lane >> 3);          // 0..127
        vp[c] = Vbase + (size_t)drow * S_LEN + ((lane & 7) ^ (drow & 7)) * 8;
    }

    const int NT = qt + 1;   // number of 64-wide kv tiles

#define STAGE(BUF) do {                                                        \
    unsigned short* kd = &Ks[BUF][0];                                          \
    unsigned short* vd = &Vs[BUF][0];                                          \
    _Pragma("unroll")                                                          \
    for (int c = 0; c < 4; ++c) {                                              \
        const int bI = w * 4 + c;                                              \
        __builtin_amdgcn_global_load_lds(                                      \
            (const __attribute__((address_space(1))) void*)kp[c],              \
            (__attribute__((address_space(3))) void*)(kd + bI * 512), 16, 0, 0);\
        __builtin_amdgcn_global_load_lds(                                      \
            (const __attribute__((address_space(1))) void*)vp[c],              \
            (__attribute__((address_space(3))) void*)(vd + bI * 512), 16, 0, 0);\
        kp[c] += 64 * HD; vp[c] += 64;                                         \
    }                                                                          \
} while (0)

    // prologue: stage tile 0
    STAGE(0);
    asm volatile("s_waitcnt vmcnt(0)" ::: "memory");
    __builtin_amdgcn_s_barrier();
    asm volatile("" ::: "memory");

    // hoisted per-lane LDS bases (all loop-invariant)
    unsigned short* pw  = &Ps[w][0];
    unsigned short* pst = pw + quad * 288 + l16;          // store base: row quad*4, col l16
    const unsigned short* prd = pw + l16 * 72 + quad * 8; // read base: row l16, k quad*8

    int cur = 0;
    for (int t = 0; t < NT; ++t) {
        if (t + 1 < NT) STAGE(cur ^ 1);     // issue next tile; latency hides under compute

        const bool diag = (t == qt);        // only the last tile crosses the causal diagonal
        const int kv0 = t << 6;
        const unsigned short* Kc = &Ks[cur][0];
        const unsigned short* Vc = &Vs[cur][0];

        // ---- QK^T: 4 n-tiles x 4 k-chunks ----
        floatx4 sacc[4];
#pragma unroll
        for (int nb = 0; nb < 4; nb++) sacc[nb] = {0.f, 0.f, 0.f, 0.f};
        __builtin_amdgcn_s_setprio(1);
#pragma unroll
        for (int ks = 0; ks < 4; ++ks) {
#pragma unroll
            for (int nb = 0; nb < 4; ++nb) {
                const int srow = nb * 16 + l16;
                const int pc = (ks * 4 + quad) ^ (l16 & 7);
                short8 kf = *reinterpret_cast<const short8*>(Kc + srow * 128 + pc * 8);
                sacc[nb] = __builtin_amdgcn_mfma_f32_16x16x32_bf16(qf[ks], kf, sacc[nb], 0, 0, 0);
            }
        }
        __builtin_amdgcn_s_setprio(0);

        // ---- exp2 + causal mask + P store (padded rows, immediate offsets) ----
#pragma unroll
        for (int nb = 0; nb < 4; ++nb) {
            const int col = kv0 + nb * 16 + l16;
#pragma unroll
            for (int r = 0; r < 4; ++r) {
                const int row = qw0 + quad * 4 + r;
                float p = (!diag || col <= row) ? exp2f(sacc[nb][r]) : 0.0f;
                lsum[r] += p;
                pst[r * 72 + nb * 16] = f2bf(p);
            }
        }

        // ---- PV: 2 k-chunks x 8 d-tiles (wave-private Ps, no barrier) ----
        __builtin_amdgcn_s_setprio(1);
#pragma unroll
        for (int kv_sub = 0; kv_sub < 2; ++kv_sub) {
            short8 pf = *reinterpret_cast<const short8*>(prd + kv_sub * 32);
#pragma unroll
            for (int dt = 0; dt < 8; ++dt) {
                const int drow = dt * 16 + l16;
                const int pcV = (kv_sub * 4 + quad) ^ (l16 & 7);
                short8 vf = *reinterpret_cast<const short8*>(Vc + drow * 64 + pcV * 8);
                oacc[dt] = __builtin_amdgcn_mfma_f32_16x16x32_bf16(pf, vf, oacc[dt], 0, 0, 0);
            }
        }
        __builtin_amdgcn_s_setprio(0);

        // drain this iter's prefetch + sync all waves; next iter may overwrite buf[cur]
        asm volatile("s_waitcnt vmcnt(0)" ::: "memory");
        __builtin_amdgcn_s_barrier();
        asm volatile("" ::: "memory");
        cur ^= 1;
    }
#undef STAGE

    // ---- final row-sum reduce + write ----
    float linv[4];
#pragma unroll
    for (int r = 0; r < 4; ++r) {
        float s = lsum[r];
#pragma unroll
        for (int off = 1; off < 16; off <<= 1) s += __shfl_xor(s, off);
        linv[r] = 1.0f / s;
    }
#pragma unroll
    for (int dt = 0; dt < 8; ++dt) {
        const int d = dt * 16 + l16;
#pragma unroll
        for (int r = 0; r < 4; ++r) {
            const int row = qw0 + quad * 4 + r;
            Ob[((size_t)(b * S_LEN + row)) * 4096 + h * 128 + d] = f2bf(oacc[dt][r] * linv[r]);
        }
    }
}

extern "C" void kernel_launch(void* const* d_in, const int* in_sizes, int n_in,
                              void* d_out, int out_size, void* d_ws, size_t ws_size,
                              hipStream_t stream) {
    const float* u     = (const float*)d_in[0];
    const float* W_in  = (const float*)d_in[1];
    const float* W_out = (const float*)d_in[2];
    float* out = (float*)d_out;

    char* ws = (char*)d_ws;
    unsigned short* u_bf    = (unsigned short*)(ws);                    //  16,777,216 B
    unsigned short* win_bf  = (unsigned short*)(ws + 16777216);         //  25,165,824 B
    unsigned short* wout_bf = (unsigned short*)(ws + 41943040);         //  16,777,216 B
    unsigned short* Z       = (unsigned short*)(ws + 58720256);         //  50,331,648 B
    unsigned short* Qb      = (unsigned short*)(ws + 109051904);        //  33,554,432 B
    unsigned short* Kv      = (unsigned short*)(ws + 142606336);        //   8,388,608 B
    unsigned short* Vt      = (unsigned short*)(ws + 150994944);        //   8,388,608 B
    unsigned short* Ob      = (unsigned short*)(ws + 159383552);        //  33,554,432 B
    // total: 192,937,984 B

    {   // casts
        int n4 = (2 * 2048 * 2048) / 4;
        cast_f32_bf16<<<(n4 + 255) / 256, 256, 0, stream>>>(u, u_bf, n4);
        n4 = (6144 * 2048) / 4;   // only the used rows [4096,10240) of W_in
        cast_f32_bf16<<<(n4 + 255) / 256, 256, 0, stream>>>(W_in + (size_t)4096 * 2048, win_bf, n4);
        n4 = (2048 * 4096) / 4;
        cast_f32_bf16<<<(n4 + 255) / 256, 256, 0, stream>>>(W_out, wout_bf, n4);
    }
    {   // GEMM1: Z[4096,6144] = u_bf[4096,2048] @ win_bf[6144,2048]^T
        dim3 g(6144 / 128, 4096 / 128);
        gemm_bt<1><<<g, 256, 0, stream>>>(u_bf, win_bf, Z, 4096, 6144, 2048);
    }
    {   // RoPE + split
        int n = BATCH * S_LEN * 3584;
        rope_split<<<(n + 255) / 256, 256, 0, stream>>>(Z, Qb, Kv, Vt);
    }
    // attention: grid = (S/64) * B * NH, heavy q-tiles first
    attn_kernel<<<BATCH * NH * (S_LEN / 64), 256, 0, stream>>>(Qb, Kv, Vt, Ob);
    {   // GEMM2: out[4096,2048] = Ob[4096,4096] @ wout_bf[2048,4096]^T  (fp32 store)
        dim3 g(2048 / 128, 4096 / 128);
        gemm_bt<0><<<g, 256, 0, stream>>>(Ob, wout_bf, out, 4096, 2048, 4096);
    }
}

// Round 2
// 549.198 us; speedup vs baseline: 1.0200x; 1.0200x over previous
//
#include <hip/hip_runtime.h>
#include <stdint.h>

#define S_LEN 2048
#define BATCH 2
#define NH 32
#define NKV 8
#define HD 128
#define NE 6144   // extracted columns of zxbcdt: x(1024) | B(1024) | C(4096)

typedef __attribute__((ext_vector_type(8))) short short8;
typedef __attribute__((ext_vector_type(4))) float floatx4;

__device__ __forceinline__ unsigned short f2bf(float f) {
    union { float f; uint32_t u; } v; v.f = f;
    uint32_t u = v.u;
    u += 0x7FFFu + ((u >> 16) & 1u);   // RTN-even (inputs are finite)
    return (unsigned short)(u >> 16);
}
__device__ __forceinline__ float bf2f(unsigned short h) {
    union { uint32_t u; float f; } v; v.u = ((uint32_t)h) << 16;
    return v.f;
}
__device__ __forceinline__ uint32_t cvt_pk_bf16(float lo, float hi) {
    uint32_t r;
    asm("v_cvt_pk_bf16_f32 %0, %1, %2" : "=v"(r) : "v"(lo), "v"(hi));
    return r;
}

// ---------------- cast fp32 -> bf16, 4 elems/thread ----------------
__global__ void cast_f32_bf16(const float* __restrict__ in,
                              unsigned short* __restrict__ out, int n4) {
    int i = blockIdx.x * blockDim.x + threadIdx.x;
    if (i >= n4) return;
    float4 f = reinterpret_cast<const float4*>(in)[i];
    ushort4 o;
    o.x = f2bf(f.x); o.y = f2bf(f.y); o.z = f2bf(f.z); o.w = f2bf(f.w);
    reinterpret_cast<ushort4*>(out)[i] = o;
}

// ---------------- m97-style B^T GEMM: C[M,N] = A[M,K] * Bt[N,K]^T ----------------
template <int OUT_BF16>
__global__ void __launch_bounds__(256)
gemm_bt(const unsigned short* __restrict__ A, const unsigned short* __restrict__ Bt,
        void* __restrict__ Cv, int M, int N, int K) {
    __shared__ unsigned short As[128 * 32];
    __shared__ unsigned short Bs[128 * 32];
    const int tid  = threadIdx.x;
    const int w    = tid >> 6;
    const int lane = tid & 63;
    const int quad = lane >> 4;
    const int l16  = lane & 15;
    const int wm   = w >> 1, wn = w & 1;
    const int m0 = blockIdx.y * 128, n0 = blockIdx.x * 128;

    floatx4 acc[4][4];
#pragma unroll
    for (int i = 0; i < 4; i++)
#pragma unroll
        for (int j = 0; j < 4; j++) acc[i][j] = {0.f, 0.f, 0.f, 0.f};

    const int lr = lane >> 2;        // row within 16-row chunk
    const int lk = (lane & 3) * 8;   // k-elem offset within 32
    const int KT = K >> 5;

    for (int kt = 0; kt < KT; ++kt) {
        const int k0 = kt << 5;
        __syncthreads();
#pragma unroll
        for (int c = 0; c < 2; ++c) {
            const int chunk = w * 2 + c;  // wave-uniform
            const unsigned short* ga = A  + (size_t)(m0 + chunk * 16 + lr) * K + k0 + lk;
            __builtin_amdgcn_global_load_lds(
                (const __attribute__((address_space(1))) void*)ga,
                (__attribute__((address_space(3))) void*)(As + chunk * 512), 16, 0, 0);
            const unsigned short* gb = Bt + (size_t)(n0 + chunk * 16 + lr) * K + k0 + lk;
            __builtin_amdgcn_global_load_lds(
                (const __attribute__((address_space(1))) void*)gb,
                (__attribute__((address_space(3))) void*)(Bs + chunk * 512), 16, 0, 0);
        }
        __syncthreads();
        short8 af[4], bf[4];
#pragma unroll
        for (int t = 0; t < 4; ++t) {
            af[t] = *reinterpret_cast<const short8*>(As + (wm * 64 + t * 16 + l16) * 32 + quad * 8);
            bf[t] = *reinterpret_cast<const short8*>(Bs + (wn * 64 + t * 16 + l16) * 32 + quad * 8);
        }
#pragma unroll
        for (int i = 0; i < 4; i++)
#pragma unroll
            for (int j = 0; j < 4; j++)
                acc[i][j] = __builtin_amdgcn_mfma_f32_16x16x32_bf16(af[i], bf[j], acc[i][j], 0, 0, 0);
    }

#pragma unroll
    for (int i = 0; i < 4; i++)
#pragma unroll
        for (int j = 0; j < 4; j++) {
            const int row = m0 + wm * 64 + i * 16 + quad * 4;
            const int col = n0 + wn * 64 + j * 16 + l16;
#pragma unroll
            for (int r = 0; r < 4; r++) {
                float vv = acc[i][j][r];
                if (OUT_BF16)
                    ((unsigned short*)Cv)[(size_t)(row + r) * N + col] = f2bf(vv);
                else
                    ((float*)Cv)[(size_t)(row + r) * N + col] = vv;
            }
        }
}

// ---------------- RoPE + split/reshape ----------------
// Z: [4096 tokens][6144] bf16. Q[B,NH,S,HD] (pre-scaled by log2e/sqrt(128)),
// K[B,NKV,S,HD], Vt[B,NKV,HD,S] with s-within-64 PERMUTED to pair order:
// k' = (k&32) + (k&15)*2 + ((k>>4)&1  -- matches attn's pair-packed P layout
// (P and V contracted over the same permuted k ordering => result unchanged).
#define QSCALE 0.12748539509360f   // log2(e) / sqrt(128)
__global__ void rope_split(const unsigned short* __restrict__ Z,
                           unsigned short* __restrict__ Q,
                           unsigned short* __restrict__ Kb,
                           unsigned short* __restrict__ Vt) {
    const int PER_TOK = 2048 + 512 + 1024;  // q-pairs + k-pairs + v-elems
    int idx = blockIdx.x * blockDim.x + threadIdx.x;
    if (idx >= BATCH * S_LEN * PER_TOK) return;
    int t = idx / PER_TOK;
    int r = idx - t * PER_TOK;
    int b = t / S_LEN, s = t - b * S_LEN;
    const unsigned short* z = Z + (size_t)t * NE;
    if (r < 2048) {                 // q pair: C section
        int h = r >> 6, j = r & 63;
        float x0 = bf2f(z[2048 + h * 128 + j]);
        float x1 = bf2f(z[2048 + h * 128 + j + 64]);
        float inv = exp2f((float)j * -0.20762050593f);   // 10000^(-j/64)
        float c, sn; sincosf((float)s * inv, &sn, &c);
        size_t base = ((size_t)(b * NH + h) * S_LEN + s) * HD;
        Q[base + j]      = f2bf((x0 * c - x1 * sn) * QSCALE);
        Q[base + j + 64] = f2bf((x1 * c + x0 * sn) * QSCALE);
    } else if (r < 2560) {          // k pair: B section
        int rr = r - 2048; int kh = rr >> 6, j = rr & 63;
        float x0 = bf2f(z[1024 + kh * 128 + j]);
        float x1 = bf2f(z[1024 + kh * 128 + j + 64]);
        float inv = exp2f((float)j * -0.20762050593f);
        float c, sn; sincosf((float)s * inv, &sn, &c);
        size_t base = ((size_t)(b * NKV + kh) * S_LEN + s) * HD;
        Kb[base + j]      = f2bf(x0 * c - x1 * sn);
        Kb[base + j + 64] = f2bf(x1 * c + x0 * sn);
    } else {                        // v elem: x section, transposed+permuted store
        int m = r - 2560; int kh = m >> 7, d = m & 127;
        int k = s & 63;
        int kp = (k & 32) + ((k & 15) << 1) + ((k >> 4) & 1);
        int sp = (s & ~63) | kp;
        Vt[((size_t)(b * NKV + kh) * HD + d) * S_LEN + sp] = z[m];
    }
}

// ---------------- Flash attention v2 (causal, GQA 4:1) ----------------
// Block = 4 waves, one (b,h,qt): 64 q rows. Single-buffered KV tiles of 64 in
// LDS (global_load_lds w16, XOR chunk-swizzle chunk^(row&7)) -- 40 KB total =
// 4 blocks/CU; inter-block TLP hides the staging drain (R1 showed dbuf's
// occupancy cost exceeds its pipelining gain).
// VALU diet vs R0: (1) P stored as packed bf16 PAIRS via v_cvt_pk_bf16_f32 +
// b32 stores (k-order pair-permuted, V permuted to match in rope_split);
// (2) causal mask only in the split-out diagonal tile; (3) setprio around MFMA.
// No online max: Q pre-scaled to log2 domain, p = exp2(t) directly.
template <bool DIAG>
__device__ __forceinline__ void attn_tile(
    const short8 (&qf)[4], floatx4 (&oacc)[8], float (&lsum)[4],
    const unsigned short* __restrict__ Ks, const unsigned short* __restrict__ Vs,
    unsigned short* __restrict__ pw, int w, int quad, int l16) {
    const int e = l16 & 7;

    // ---- QK^T: 4 n-tiles x 4 k-chunks ----
    floatx4 sacc[4];
#pragma unroll
    for (int nb = 0; nb < 4; nb++) sacc[nb] = {0.f, 0.f, 0.f, 0.f};
    __builtin_amdgcn_s_setprio(1);
#pragma unroll
    for (int ks = 0; ks < 4; ++ks) {
#pragma unroll
        for (int nb = 0; nb < 4; ++nb) {
            const int srow = nb * 16 + l16;
            const int pc = (ks * 4 + quad) ^ e;
            short8 kf = *reinterpret_cast<const short8*>(Ks + srow * 128 + pc * 8);
            sacc[nb] = __builtin_amdgcn_mfma_f32_16x16x32_bf16(qf[ks], kf, sacc[nb], 0, 0, 0);
        }
    }
    __builtin_amdgcn_s_setprio(0);

    // ---- exp2 (+ causal mask only on diagonal tile) ----
    float pv[4][4];
#pragma unroll
    for (int nb = 0; nb < 4; ++nb)
#pragma unroll
        for (int r = 0; r < 4; ++r) {
            float p = exp2f(sacc[nb][r]);
            if (DIAG)
                p = (nb * 16 + l16 <= w * 16 + quad * 4 + r) ? p : 0.0f;
            pv[nb][r] = p;
            lsum[r] += p;
        }

    // ---- P store: pair-packed b32, XOR chunk swizzle (2-way, free) ----
    const int row0 = quad * 4;
    const int sub = l16 >> 2, off = (l16 & 3) * 2;
#pragma unroll
    for (int r = 0; r < 4; ++r) {
        const int rowe = (row0 + r) & 7;
#pragma unroll
        for (int g = 0; g < 2; ++g) {
            uint32_t pk = cvt_pk_bf16(pv[g * 2][r], pv[g * 2 + 1][r]);
            const int chunk = (g * 4 + sub) ^ rowe;
            *reinterpret_cast<uint32_t*>(pw + (row0 + r) * 64 + chunk * 8 + off) = pk;
        }
    }

    // ---- PV: 2 k-chunks x 8 d-tiles (wave-private Ps, no barrier) ----
    __builtin_amdgcn_s_setprio(1);
#pragma unroll
    for (int kv_sub = 0; kv_sub < 2; ++kv_sub) {
        const int pcP = (kv_sub * 4 + quad) ^ e;
        short8 pf = *reinterpret_cast<const short8*>(pw + l16 * 64 + pcP * 8);
#pragma unroll
        for (int dt = 0; dt < 8; ++dt) {
            const int drow = dt * 16 + l16;
            const int pcV = (kv_sub * 4 + quad) ^ e;
            short8 vf = *reinterpret_cast<const short8*>(Vs + drow * 64 + pcV * 8);
            oacc[dt] = __builtin_amdgcn_mfma_f32_16x16x32_bf16(pf, vf, oacc[dt], 0, 0, 0);
        }
    }
    __builtin_amdgcn_s_setprio(0);
}

__global__ void __launch_bounds__(256, 4)
attn_kernel(const unsigned short* __restrict__ Q,
            const unsigned short* __restrict__ Kb,
            const unsigned short* __restrict__ Vt,
            unsigned short* __restrict__ Ob) {
    __shared__ unsigned short Ks[64 * 128];   // [s][d] swizzled, 16 KB
    __shared__ unsigned short Vs[128 * 64];   // [d][s'] swizzled, 16 KB
    __shared__ unsigned short Ps[4][16 * 64]; // per-wave P, swizzled, 8 KB
    const int tid  = threadIdx.x;
    const int w    = tid >> 6;
    const int lane = tid & 63;
    const int quad = lane >> 4;
    const int l16  = lane & 15;
    const int blk = blockIdx.x;
    const int qt = 31 - (blk >> 6);      // heavy blocks dispatch first
    const int bh = blk & 63;
    const int h = bh & 31, b = bh >> 5;
    const int kvh = h >> 2;
    const int qw0 = qt * 64 + w * 16;

    const unsigned short* Qbase = Q  + ((size_t)(b * NH  + h)   * S_LEN) * HD;
    const unsigned short* Kbase = Kb + ((size_t)(b * NKV + kvh) * S_LEN) * HD;
    const unsigned short* Vbase = Vt + ((size_t)(b * NKV + kvh) * HD) * S_LEN;

    short8 qf[4];
    {
        const unsigned short* qrow = Qbase + (size_t)(qw0 + l16) * HD + quad * 8;
#pragma unroll
        for (int ks = 0; ks < 4; ++ks)
            qf[ks] = *reinterpret_cast<const short8*>(qrow + ks * 32);
    }

    floatx4 oacc[8];
#pragma unroll
    for (int i = 0; i < 8; i++) oacc[i] = {0.f, 0.f, 0.f, 0.f};
    float lsum[4] = {0.f, 0.f, 0.f, 0.f};

    // per-lane staging pointers, advanced one KV tile per STAGE
    const unsigned short* kp[4];
    const unsigned short* vp[4];
#pragma unroll
    for (int c = 0; c < 4; ++c) {
        const int bI = w * 4 + c;                       // wave-uniform block idx
        const int krow = bI * 4 + (lane >> 4);          // 0..63
        kp[c] = Kbase + (size_t)krow * HD + ((lane & 15) ^ (krow & 7)) * 8;
        const int drow = bI * 8 + (lane >> 3);          // 0..127
        vp[c] = Vbase + (size_t)drow * S_LEN + ((lane & 7) ^ (drow & 7)) * 8;
    }

#define STAGE() do {                                                           \
    _Pragma("unroll")                                                          \
    for (int c = 0; c < 4; ++c) {                                              \
        const int bI = w * 4 + c;                                              \
        __builtin_amdgcn_global_load_lds(                                      \
            (const __attribute__((address_space(1))) void*)kp[c],              \
            (__attribute__((address_space(3))) void*)(Ks + bI * 512), 16, 0, 0);\
        __builtin_amdgcn_global_load_lds(                                      \
            (const __attribute__((address_space(1))) void*)vp[c],              \
            (__attribute__((address_space(3))) void*)(Vs + bI * 512), 16, 0, 0);\
        kp[c] += 64 * HD; vp[c] += 64;                                         \
    }                                                                          \
} while (0)

    unsigned short* pw = &Ps[w][0];

    // main loop: tiles strictly below the diagonal block -> no masking
    for (int t = 0; t < qt; ++t) {
        __syncthreads();   // previous-iter LDS reads done before overwrite
        STAGE();
        __syncthreads();   // staging complete
        attn_tile<false>(qf, oacc, lsum, Ks, Vs, pw, w, quad, l16);
    }
    // diagonal tile: masked
    __syncthreads();
    STAGE();
    __syncthreads();
    attn_tile<true>(qf, oacc, lsum, Ks, Vs, pw, w, quad, l16);
#undef STAGE

    // ---- final row-sum reduce + write ----
    float linv[4];
#pragma unroll
    for (int r = 0; r < 4; ++r) {
        float s = lsum[r];
#pragma unroll
        for (int off = 1; off < 16; off <<= 1) s += __shfl_xor(s, off);
        linv[r] = 1.0f / s;
    }
#pragma unroll
    for (int dt = 0; dt < 8; ++dt) {
        const int d = dt * 16 + l16;
#pragma unroll
        for (int r = 0; r < 4; ++r) {
            const int row = qw0 + quad * 4 + r;
            Ob[((size_t)(b * S_LEN + row)) * 4096 + h * 128 + d] = f2bf(oacc[dt][r] * linv[r]);
        }
    }
}

extern "C" void kernel_launch(void* const* d_in, const int* in_sizes, int n_in,
                              void* d_out, int out_size, void* d_ws, size_t ws_size,
                              hipStream_t stream) {
    const float* u     = (const float*)d_in[0];
    const float* W_in  = (const float*)d_in[1];
    const float* W_out = (const float*)d_in[2];
    float* out = (float*)d_out;

    char* ws = (char*)d_ws;
    unsigned short* u_bf    = (unsigned short*)(ws);                    //  16,777,216 B
    unsigned short* win_bf  = (unsigned short*)(ws + 16777216);         //  25,165,824 B
    unsigned short* wout_bf = (unsigned short*)(ws + 41943040);         //  16,777,216 B
    unsigned short* Z       = (unsigned short*)(ws + 58720256);         //  50,331,648 B
    unsigned short* Qb      = (unsigned short*)(ws + 109051904);        //  33,554,432 B
    unsigned short* Kv      = (unsigned short*)(ws + 142606336);        //   8,388,608 B
    unsigned short* Vt      = (unsigned short*)(ws + 150994944);        //   8,388,608 B
    unsigned short* Ob      = (unsigned short*)(ws + 159383552);        //  33,554,432 B
    // total: 192,937,984 B

    {   // casts
        int n4 = (2 * 2048 * 2048) / 4;
        cast_f32_bf16<<<(n4 + 255) / 256, 256, 0, stream>>>(u, u_bf, n4);
        n4 = (6144 * 2048) / 4;   // only the used rows [4096,10240) of W_in
        cast_f32_bf16<<<(n4 + 255) / 256, 256, 0, stream>>>(W_in + (size_t)4096 * 2048, win_bf, n4);
        n4 = (2048 * 4096) / 4;
        cast_f32_bf16<<<(n4 + 255) / 256, 256, 0, stream>>>(W_out, wout_bf, n4);
    }
    {   // GEMM1: Z[4096,6144] = u_bf[4096,2048] @ win_bf[6144,2048]^T
        dim3 g(6144 / 128, 4096 / 128);
        gemm_bt<1><<<g, 256, 0, stream>>>(u_bf, win_bf, Z, 4096, 6144, 2048);
    }
    {   // RoPE + split (V stored s-within-64 pair-permuted)
        int n = BATCH * S_LEN * 3584;
        rope_split<<<(n + 255) / 256, 256, 0, stream>>>(Z, Qb, Kv, Vt);
    }
    // attention: grid = (S/64) * B * NH, heavy q-tiles first
    attn_kernel<<<BATCH * NH * (S_LEN / 64), 256, 0, stream>>>(Qb, Kv, Vt, Ob);
    {   // GEMM2: out[4096,2048] = Ob[4096,4096] @ wout_bf[2048,4096]^T  (fp32 store)
        dim3 g(2048 / 128, 4096 / 128);
        gemm_bt<0><<<g, 256, 0, stream>>>(Ob, wout_bf, out, 2048 == 2048 ? 4096 : 4096, 2048, 4096);
    }
}

// Round 3
// 547.196 us; speedup vs baseline: 1.0238x; 1.0037x over previous
//
#include <hip/hip_runtime.h>
#include <stdint.h>

#define S_LEN 2048
#define BATCH 2
#define NH 32
#define NKV 8
#define HD 128
#define NE 6144   // extracted columns of zxbcdt: x(1024) | B(1024) | C(4096)

typedef __attribute__((ext_vector_type(8))) short short8;
typedef __attribute__((ext_vector_type(4))) float floatx4;

__device__ __forceinline__ unsigned short f2bf(float f) {
    union { float f; uint32_t u; } v; v.f = f;
    uint32_t u = v.u;
    u += 0x7FFFu + ((u >> 16) & 1u);   // RTN-even (inputs are finite)
    return (unsigned short)(u >> 16);
}
__device__ __forceinline__ float bf2f(unsigned short h) {
    union { uint32_t u; float f; } v; v.u = ((uint32_t)h) << 16;
    return v.f;
}
__device__ __forceinline__ uint32_t cvt_pk_bf16(float lo, float hi) {
    uint32_t r;
    asm("v_cvt_pk_bf16_f32 %0, %1, %2" : "=v"(r) : "v"(lo), "v"(hi));
    return r;
}

// ---------------- cast fp32 -> bf16, 4 elems/thread ----------------
__global__ void cast_f32_bf16(const float* __restrict__ in,
                              unsigned short* __restrict__ out, int n4) {
    int i = blockIdx.x * blockDim.x + threadIdx.x;
    if (i >= n4) return;
    float4 f = reinterpret_cast<const float4*>(in)[i];
    ushort4 o;
    o.x = f2bf(f.x); o.y = f2bf(f.y); o.z = f2bf(f.z); o.w = f2bf(f.w);
    reinterpret_cast<ushort4*>(out)[i] = o;
}

// ---------------- m97-style B^T GEMM (kept for GEMM2): C[M,N] = A*Bt^T ----------------
template <int OUT_BF16>
__global__ void __launch_bounds__(256)
gemm_bt(const unsigned short* __restrict__ A, const unsigned short* __restrict__ Bt,
        void* __restrict__ Cv, int M, int N, int K) {
    __shared__ unsigned short As[128 * 32];
    __shared__ unsigned short Bs[128 * 32];
    const int tid  = threadIdx.x;
    const int w    = tid >> 6;
    const int lane = tid & 63;
    const int quad = lane >> 4;
    const int l16  = lane & 15;
    const int wm   = w >> 1, wn = w & 1;
    const int m0 = blockIdx.y * 128, n0 = blockIdx.x * 128;

    floatx4 acc[4][4];
#pragma unroll
    for (int i = 0; i < 4; i++)
#pragma unroll
        for (int j = 0; j < 4; j++) acc[i][j] = {0.f, 0.f, 0.f, 0.f};

    const int lr = lane >> 2;        // row within 16-row chunk
    const int lk = (lane & 3) * 8;   // k-elem offset within 32
    const int KT = K >> 5;

    for (int kt = 0; kt < KT; ++kt) {
        const int k0 = kt << 5;
        __syncthreads();
#pragma unroll
        for (int c = 0; c < 2; ++c) {
            const int chunk = w * 2 + c;  // wave-uniform
            const unsigned short* ga = A  + (size_t)(m0 + chunk * 16 + lr) * K + k0 + lk;
            __builtin_amdgcn_global_load_lds(
                (const __attribute__((address_space(1))) void*)ga,
                (__attribute__((address_space(3))) void*)(As + chunk * 512), 16, 0, 0);
            const unsigned short* gb = Bt + (size_t)(n0 + chunk * 16 + lr) * K + k0 + lk;
            __builtin_amdgcn_global_load_lds(
                (const __attribute__((address_space(1))) void*)gb,
                (__attribute__((address_space(3))) void*)(Bs + chunk * 512), 16, 0, 0);
        }
        __syncthreads();
        short8 af[4], bf[4];
#pragma unroll
        for (int t = 0; t < 4; ++t) {
            af[t] = *reinterpret_cast<const short8*>(As + (wm * 64 + t * 16 + l16) * 32 + quad * 8);
            bf[t] = *reinterpret_cast<const short8*>(Bs + (wn * 64 + t * 16 + l16) * 32 + quad * 8);
        }
#pragma unroll
        for (int i = 0; i < 4; i++)
#pragma unroll
            for (int j = 0; j < 4; j++)
                acc[i][j] = __builtin_amdgcn_mfma_f32_16x16x32_bf16(af[i], bf[j], acc[i][j], 0, 0, 0);
    }

#pragma unroll
    for (int i = 0; i < 4; i++)
#pragma unroll
        for (int j = 0; j < 4; j++) {
            const int row = m0 + wm * 64 + i * 16 + quad * 4;
            const int col = n0 + wn * 64 + j * 16 + l16;
#pragma unroll
            for (int r = 0; r < 4; r++) {
                float vv = acc[i][j][r];
                if (OUT_BF16)
                    ((unsigned short*)Cv)[(size_t)(row + r) * N + col] = f2bf(vv);
                else
                    ((float*)Cv)[(size_t)(row + r) * N + col] = vv;
            }
        }
}

// ---------------- 256x256 8-phase GEMM (T2+T3+T4+T5), bf16 out ----------------
// C[M,N] = A[M,K] * Bt[N,K]^T. 512 threads = 8 waves (2M x 4N), BK=64,
// 2 K-tile LDS buffers (128 KB -> 1 block/CU). Per K-tile, 4 phases:
//  ph1: ds_read A-half0(8)+B-half0(4) -> 16 MFMA quad(0,0)
//  ph2: ds_read A-half1(8)+B-half1(4) -> quad(1,0)      [all buf reads done]
//  ph3: stage tile t+2 A-halves (4 gload_lds)           -> quad(1,1)
//  ph4: stage tile t+2 B-halves (4 gload_lds)           -> quad(0,1)
// vmcnt(8) once per K-tile (next tile's 8 loads stay in flight), raw
// s_barrier (no __syncthreads vmcnt-drain). st_16x32 swizzle: LDS linear,
// global SOURCE col pre-swizzled (rule #21), ds_read applies same XOR.
__device__ __forceinline__ short8 ldfrag256(const unsigned short* base, int row, int k8) {
    const int c8 = k8 ^ ((row & 4) ? 2 : 0);    // st_16x32: byte ^= ((byte>>9)&1)<<5
    return *reinterpret_cast<const short8*>(base + row * 64 + c8 * 8);
}

__global__ void __launch_bounds__(512, 2)
gemm256_bt(const unsigned short* __restrict__ A, const unsigned short* __restrict__ Bt,
           unsigned short* __restrict__ C, int M, int N, int K) {
    __shared__ unsigned short As[2][256 * 64];   // 64 KB
    __shared__ unsigned short Bs[2][256 * 64];   // 64 KB
    const int tid  = threadIdx.x;
    const int w    = tid >> 6;
    const int lane = tid & 63;
    const int quad = lane >> 4;
    const int l16  = lane & 15;
    const int wm   = w >> 2, wn = w & 3;

    // bijective XCD swizzle (nwg % 8 == 0 for our grids)
    const int nwg = gridDim.x * gridDim.y;
    const int cpx = nwg >> 3;
    const int lin = blockIdx.y * gridDim.x + blockIdx.x;
    const int swz = (lin & 7) * cpx + (lin >> 3);
    const int ntx = N >> 8;
    const int m0 = (swz / ntx) << 8;
    const int n0 = (swz % ntx) << 8;

    floatx4 acc[8][4];
#pragma unroll
    for (int i = 0; i < 8; i++)
#pragma unroll
        for (int j = 0; j < 4; j++) acc[i][j] = {0.f, 0.f, 0.f, 0.f};

    // staging: each wave stages rows {w*16 + c*8 + (lane>>3)} of each 128-row half.
    // source col8 pre-swizzled: c8' = (lane&7) ^ (bit2(row-in-8)<<1)
    const int l8  = lane >> 3;
    const int c8s = (lane & 7) ^ (((lane >> 5) & 1) << 1);
    const unsigned short* apA = A  + (size_t)(m0 + w * 16 + l8) * K + c8s * 8;
    const unsigned short* apB = Bt + (size_t)(n0 + w * 16 + l8) * K + c8s * 8;

#define GLD256(src, dst) __builtin_amdgcn_global_load_lds(                     \
    (const __attribute__((address_space(1))) void*)(src),                      \
    (__attribute__((address_space(3))) void*)(dst), 16, 0, 0)

#define STAGE_A256(bufi, t) do {                                               \
    unsigned short* d = &As[bufi][w * 16 * 64];                                \
    const unsigned short* s = apA + (size_t)(t) * 64;                          \
    GLD256(s,                    d);                                           \
    GLD256(s + (size_t)8 * K,    d + 8 * 64);                                  \
    GLD256(s + (size_t)128 * K,  d + 128 * 64);                                \
    GLD256(s + (size_t)136 * K,  d + 136 * 64);                                \
} while (0)

#define STAGE_B256(bufi, t) do {                                               \
    unsigned short* d = &Bs[bufi][w * 16 * 64];                                \
    const unsigned short* s = apB + (size_t)(t) * 64;                          \
    GLD256(s,                    d);                                           \
    GLD256(s + (size_t)8 * K,    d + 8 * 64);                                  \
    GLD256(s + (size_t)128 * K,  d + 128 * 64);                                \
    GLD256(s + (size_t)136 * K,  d + 136 * 64);                                \
} while (0)

    // prologue: stage tiles 0 and 1
    STAGE_A256(0, 0); STAGE_B256(0, 0);
    STAGE_A256(1, 1); STAGE_B256(1, 1);

    short8 a0[8], a1[8], b0[4], b1[4];
    const int NT = K >> 6;

#pragma unroll 1
    for (int t = 0; t < NT; ++t) {
        const int buf = t & 1;
        const unsigned short* Ab = &As[buf][0];
        const unsigned short* Bb = &Bs[buf][0];

        // top wait: own loads for tile t complete (tile t+1's 8 may stay in flight)
        if (t < NT - 1) { asm volatile("s_waitcnt vmcnt(8)" ::: "memory"); }
        else            { asm volatile("s_waitcnt vmcnt(0)" ::: "memory"); }
        __builtin_amdgcn_s_barrier();     // all waves' tile-t loads landed
        asm volatile("" ::: "memory");

        // ---- ph1: A-half0 + B-half0 ----
#pragma unroll
        for (int mi = 0; mi < 4; ++mi) {
            const int row = wm * 128 + mi * 16 + l16;
            a0[mi * 2 + 0] = ldfrag256(Ab, row, quad);
            a0[mi * 2 + 1] = ldfrag256(Ab, row, 4 + quad);
        }
#pragma unroll
        for (int ni = 0; ni < 2; ++ni) {
            const int row = wn * 64 + ni * 16 + l16;
            b0[ni * 2 + 0] = ldfrag256(Bb, row, quad);
            b0[ni * 2 + 1] = ldfrag256(Bb, row, 4 + quad);
        }
        asm volatile("" ::: "memory");
        __builtin_amdgcn_s_barrier();
        __builtin_amdgcn_s_setprio(1);
#pragma unroll
        for (int mi = 0; mi < 4; ++mi)
#pragma unroll
            for (int ni = 0; ni < 2; ++ni) {
                acc[mi][ni] = __builtin_amdgcn_mfma_f32_16x16x32_bf16(a0[mi*2+0], b0[ni*2+0], acc[mi][ni], 0, 0, 0);
                acc[mi][ni] = __builtin_amdgcn_mfma_f32_16x16x32_bf16(a0[mi*2+1], b0[ni*2+1], acc[mi][ni], 0, 0, 0);
            }
        __builtin_amdgcn_s_setprio(0);
        asm volatile("" ::: "memory");
        __builtin_amdgcn_s_barrier();

        // ---- ph2: A-half1 + B-half1 ----
#pragma unroll
        for (int mi = 0; mi < 4; ++mi) {
            const int row = wm * 128 + 64 + mi * 16 + l16;
            a1[mi * 2 + 0] = ldfrag256(Ab, row, quad);
            a1[mi * 2 + 1] = ldfrag256(Ab, row, 4 + quad);
        }
#pragma unroll
        for (int ni = 0; ni < 2; ++ni) {
            const int row = wn * 64 + 32 + ni * 16 + l16;
            b1[ni * 2 + 0] = ldfrag256(Bb, row, quad);
            b1[ni * 2 + 1] = ldfrag256(Bb, row, 4 + quad);
        }
        asm volatile("" ::: "memory");
        __builtin_amdgcn_s_barrier();
        __builtin_amdgcn_s_setprio(1);
#pragma unroll
        for (int mi = 0; mi < 4; ++mi)
#pragma unroll
            for (int ni = 0; ni < 2; ++ni) {
                acc[4 + mi][ni] = __builtin_amdgcn_mfma_f32_16x16x32_bf16(a1[mi*2+0], b0[ni*2+0], acc[4+mi][ni], 0, 0, 0);
                acc[4 + mi][ni] = __builtin_amdgcn_mfma_f32_16x16x32_bf16(a1[mi*2+1], b0[ni*2+1], acc[4+mi][ni], 0, 0, 0);
            }
        __builtin_amdgcn_s_setprio(0);
        asm volatile("" ::: "memory");
        __builtin_amdgcn_s_barrier();     // all buf reads complete block-wide

        // ---- ph3: stage next-next A + quad(1,1) ----
        if (t + 2 < NT) { STAGE_A256(buf, t + 2); }
        asm volatile("" ::: "memory");
        __builtin_amdgcn_s_barrier();
        __builtin_amdgcn_s_setprio(1);
#pragma unroll
        for (int mi = 0; mi < 4; ++mi)
#pragma unroll
            for (int ni = 0; ni < 2; ++ni) {
                acc[4 + mi][2 + ni] = __builtin_amdgcn_mfma_f32_16x16x32_bf16(a1[mi*2+0], b1[ni*2+0], acc[4+mi][2+ni], 0, 0, 0);
                acc[4 + mi][2 + ni] = __builtin_amdgcn_mfma_f32_16x16x32_bf16(a1[mi*2+1], b1[ni*2+1], acc[4+mi][2+ni], 0, 0, 0);
            }
        __builtin_amdgcn_s_setprio(0);
        asm volatile("" ::: "memory");
        __builtin_amdgcn_s_barrier();     // b1 reads consumed; B-region safe

        // ---- ph4: stage next-next B + quad(0,1) ----
        if (t + 2 < NT) { STAGE_B256(buf, t + 2); }
        asm volatile("" ::: "memory");
        __builtin_amdgcn_s_setprio(1);
#pragma unroll
        for (int mi = 0; mi < 4; ++mi)
#pragma unroll
            for (int ni = 0; ni < 2; ++ni) {
                acc[mi][2 + ni] = __builtin_amdgcn_mfma_f32_16x16x32_bf16(a0[mi*2+0], b1[ni*2+0], acc[mi][2+ni], 0, 0, 0);
                acc[mi][2 + ni] = __builtin_amdgcn_mfma_f32_16x16x32_bf16(a0[mi*2+1], b1[ni*2+1], acc[mi][2+ni], 0, 0, 0);
            }
        __builtin_amdgcn_s_setprio(0);
        // no trailing barrier: next iteration's top vmcnt+barrier covers it
    }
#undef STAGE_A256
#undef STAGE_B256
#undef GLD256

    // ---- epilogue: bf16 store ----
#pragma unroll
    for (int mi = 0; mi < 8; ++mi)
#pragma unroll
        for (int ni = 0; ni < 4; ++ni) {
            const int row = m0 + wm * 128 + mi * 16 + quad * 4;
            const int col = n0 + wn * 64 + ni * 16 + l16;
#pragma unroll
            for (int r = 0; r < 4; ++r)
                C[(size_t)(row + r) * N + col] = f2bf(acc[mi][ni][r]);
        }
}

// ---------------- RoPE + split/reshape ----------------
// Z: [4096 tokens][6144] bf16. Q[B,NH,S,HD] (pre-scaled by log2e/sqrt(128)),
// K[B,NKV,S,HD], Vt[B,NKV,HD,S] with s-within-64 PERMUTED to pair order
// (matches attn's pair-packed P layout; P,V contracted over same permuted k).
#define QSCALE 0.12748539509360f   // log2(e) / sqrt(128)
__global__ void rope_split(const unsigned short* __restrict__ Z,
                           unsigned short* __restrict__ Q,
                           unsigned short* __restrict__ Kb,
                           unsigned short* __restrict__ Vt) {
    const int PER_TOK = 2048 + 512 + 1024;  // q-pairs + k-pairs + v-elems
    int idx = blockIdx.x * blockDim.x + threadIdx.x;
    if (idx >= BATCH * S_LEN * PER_TOK) return;
    int t = idx / PER_TOK;
    int r = idx - t * PER_TOK;
    int b = t / S_LEN, s = t - b * S_LEN;
    const unsigned short* z = Z + (size_t)t * NE;
    if (r < 2048) {                 // q pair: C section
        int h = r >> 6, j = r & 63;
        float x0 = bf2f(z[2048 + h * 128 + j]);
        float x1 = bf2f(z[2048 + h * 128 + j + 64]);
        float inv = exp2f((float)j * -0.20762050593f);   // 10000^(-j/64)
        float c, sn; sincosf((float)s * inv, &sn, &c);
        size_t base = ((size_t)(b * NH + h) * S_LEN + s) * HD;
        Q[base + j]      = f2bf((x0 * c - x1 * sn) * QSCALE);
        Q[base + j + 64] = f2bf((x1 * c + x0 * sn) * QSCALE);
    } else if (r < 2560) {          // k pair: B section
        int rr = r - 2048; int kh = rr >> 6, j = rr & 63;
        float x0 = bf2f(z[1024 + kh * 128 + j]);
        float x1 = bf2f(z[1024 + kh * 128 + j + 64]);
        float inv = exp2f((float)j * -0.20762050593f);
        float c, sn; sincosf((float)s * inv, &sn, &c);
        size_t base = ((size_t)(b * NKV + kh) * S_LEN + s) * HD;
        Kb[base + j]      = f2bf(x0 * c - x1 * sn);
        Kb[base + j + 64] = f2bf(x1 * c + x0 * sn);
    } else {                        // v elem: x section, transposed+permuted store
        int m = r - 2560; int kh = m >> 7, d = m & 127;
        int k = s & 63;
        int kp = (k & 32) + ((k & 15) << 1) + ((k >> 4) & 1);
        int sp = (s & ~63) | kp;
        Vt[((size_t)(b * NKV + kh) * HD + d) * S_LEN + sp] = z[m];
    }
}

// ---------------- Flash attention v2 (causal, GQA 4:1) ----------------
// (unchanged from R2: single-buffered LDS, 4 blocks/CU, pair-packed P via
// cvt_pk, diagonal-tile split, setprio around MFMA.)
template <bool DIAG>
__device__ __forceinline__ void attn_tile(
    const short8 (&qf)[4], floatx4 (&oacc)[8], float (&lsum)[4],
    const unsigned short* __restrict__ Ks, const unsigned short* __restrict__ Vs,
    unsigned short* __restrict__ pw, int w, int quad, int l16) {
    const int e = l16 & 7;

    // ---- QK^T: 4 n-tiles x 4 k-chunks ----
    floatx4 sacc[4];
#pragma unroll
    for (int nb = 0; nb < 4; nb++) sacc[nb] = {0.f, 0.f, 0.f, 0.f};
    __builtin_amdgcn_s_setprio(1);
#pragma unroll
    for (int ks = 0; ks < 4; ++ks) {
#pragma unroll
        for (int nb = 0; nb < 4; ++nb) {
            const int srow = nb * 16 + l16;
            const int pc = (ks * 4 + quad) ^ e;
            short8 kf = *reinterpret_cast<const short8*>(Ks + srow * 128 + pc * 8);
            sacc[nb] = __builtin_amdgcn_mfma_f32_16x16x32_bf16(qf[ks], kf, sacc[nb], 0, 0, 0);
        }
    }
    __builtin_amdgcn_s_setprio(0);

    // ---- exp2 (+ causal mask only on diagonal tile) ----
    float pv[4][4];
#pragma unroll
    for (int nb = 0; nb < 4; ++nb)
#pragma unroll
        for (int r = 0; r < 4; ++r) {
            float p = exp2f(sacc[nb][r]);
            if (DIAG)
                p = (nb * 16 + l16 <= w * 16 + quad * 4 + r) ? p : 0.0f;
            pv[nb][r] = p;
            lsum[r] += p;
        }

    // ---- P store: pair-packed b32, XOR chunk swizzle (2-way, free) ----
    const int row0 = quad * 4;
    const int sub = l16 >> 2, off = (l16 & 3) * 2;
#pragma unroll
    for (int r = 0; r < 4; ++r) {
        const int rowe = (row0 + r) & 7;
#pragma unroll
        for (int g = 0; g < 2; ++g) {
            uint32_t pk = cvt_pk_bf16(pv[g * 2][r], pv[g * 2 + 1][r]);
            const int chunk = (g * 4 + sub) ^ rowe;
            *reinterpret_cast<uint32_t*>(pw + (row0 + r) * 64 + chunk * 8 + off) = pk;
        }
    }

    // ---- PV: 2 k-chunks x 8 d-tiles (wave-private Ps, no barrier) ----
    __builtin_amdgcn_s_setprio(1);
#pragma unroll
    for (int kv_sub = 0; kv_sub < 2; ++kv_sub) {
        const int pcP = (kv_sub * 4 + quad) ^ e;
        short8 pf = *reinterpret_cast<const short8*>(pw + l16 * 64 + pcP * 8);
#pragma unroll
        for (int dt = 0; dt < 8; ++dt) {
            const int drow = dt * 16 + l16;
            const int pcV = (kv_sub * 4 + quad) ^ e;
            short8 vf = *reinterpret_cast<const short8*>(Vs + drow * 64 + pcV * 8);
            oacc[dt] = __builtin_amdgcn_mfma_f32_16x16x32_bf16(pf, vf, oacc[dt], 0, 0, 0);
        }
    }
    __builtin_amdgcn_s_setprio(0);
}

__global__ void __launch_bounds__(256, 4)
attn_kernel(const unsigned short* __restrict__ Q,
            const unsigned short* __restrict__ Kb,
            const unsigned short* __restrict__ Vt,
            unsigned short* __restrict__ Ob) {
    __shared__ unsigned short Ks[64 * 128];   // [s][d] swizzled, 16 KB
    __shared__ unsigned short Vs[128 * 64];   // [d][s'] swizzled, 16 KB
    __shared__ unsigned short Ps[4][16 * 64]; // per-wave P, swizzled, 8 KB
    const int tid  = threadIdx.x;
    const int w    = tid >> 6;
    const int lane = tid & 63;
    const int quad = lane >> 4;
    const int l16  = lane & 15;
    const int blk = blockIdx.x;
    const int qt = 31 - (blk >> 6);      // heavy blocks dispatch first
    const int bh = blk & 63;
    const int h = bh & 31, b = bh >> 5;
    const int kvh = h >> 2;
    const int qw0 = qt * 64 + w * 16;

    const unsigned short* Qbase = Q  + ((size_t)(b * NH  + h)   * S_LEN) * HD;
    const unsigned short* Kbase = Kb + ((size_t)(b * NKV + kvh) * S_LEN) * HD;
    const unsigned short* Vbase = Vt + ((size_t)(b * NKV + kvh) * HD) * S_LEN;

    short8 qf[4];
    {
        const unsigned short* qrow = Qbase + (size_t)(qw0 + l16) * HD + quad * 8;
#pragma unroll
        for (int ks = 0; ks < 4; ++ks)
            qf[ks] = *reinterpret_cast<const short8*>(qrow + ks * 32);
    }

    floatx4 oacc[8];
#pragma unroll
    for (int i = 0; i < 8; i++) oacc[i] = {0.f, 0.f, 0.f, 0.f};
    float lsum[4] = {0.f, 0.f, 0.f, 0.f};

    // per-lane staging pointers, advanced one KV tile per STAGE
    const unsigned short* kp[4];
    const unsigned short* vp[4];
#pragma unroll
    for (int c = 0; c < 4; ++c) {
        const int bI = w * 4 + c;                       // wave-uniform block idx
        const int krow = bI * 4 + (lane >> 4);          // 0..63
        kp[c] = Kbase + (size_t)krow * HD + ((lane & 15) ^ (krow & 7)) * 8;
        const int drow = bI * 8 + (lane >> 3);          // 0..127
        vp[c] = Vbase + (size_t)drow * S_LEN + ((lane & 7) ^ (drow & 7)) * 8;
    }

#define STAGE() do {                                                           \
    _Pragma("unroll")                                                          \
    for (int c = 0; c < 4; ++c) {                                              \
        const int bI = w * 4 + c;                                              \
        __builtin_amdgcn_global_load_lds(                                      \
            (const __attribute__((address_space(1))) void*)kp[c],              \
            (__attribute__((address_space(3))) void*)(Ks + bI * 512), 16, 0, 0);\
        __builtin_amdgcn_global_load_lds(                                      \
            (const __attribute__((address_space(1))) void*)vp[c],              \
            (__attribute__((address_space(3))) void*)(Vs + bI * 512), 16, 0, 0);\
        kp[c] += 64 * HD; vp[c] += 64;                                         \
    }                                                                          \
} while (0)

    unsigned short* pw = &Ps[w][0];

    // main loop: tiles strictly below the diagonal block -> no masking
    for (int t = 0; t < qt; ++t) {
        __syncthreads();   // previous-iter LDS reads done before overwrite
        STAGE();
        __syncthreads();   // staging complete
        attn_tile<false>(qf, oacc, lsum, Ks, Vs, pw, w, quad, l16);
    }
    // diagonal tile: masked
    __syncthreads();
    STAGE();
    __syncthreads();
    attn_tile<true>(qf, oacc, lsum, Ks, Vs, pw, w, quad, l16);
#undef STAGE

    // ---- final row-sum reduce + write ----
    float linv[4];
#pragma unroll
    for (int r = 0; r < 4; ++r) {
        float s = lsum[r];
#pragma unroll
        for (int off = 1; off < 16; off <<= 1) s += __shfl_xor(s, off);
        linv[r] = 1.0f / s;
    }
#pragma unroll
    for (int dt = 0; dt < 8; ++dt) {
        const int d = dt * 16 + l16;
#pragma unroll
        for (int r = 0; r < 4; ++r) {
            const int row = qw0 + quad * 4 + r;
            Ob[((size_t)(b * S_LEN + row)) * 4096 + h * 128 + d] = f2bf(oacc[dt][r] * linv[r]);
        }
    }
}

extern "C" void kernel_launch(void* const* d_in, const int* in_sizes, int n_in,
                              void* d_out, int out_size, void* d_ws, size_t ws_size,
                              hipStream_t stream) {
    const float* u     = (const float*)d_in[0];
    const float* W_in  = (const float*)d_in[1];
    const float* W_out = (const float*)d_in[2];
    float* out = (float*)d_out;

    char* ws = (char*)d_ws;
    unsigned short* u_bf    = (unsigned short*)(ws);                    //  16,777,216 B
    unsigned short* win_bf  = (unsigned short*)(ws + 16777216);         //  25,165,824 B
    unsigned short* wout_bf = (unsigned short*)(ws + 41943040);         //  16,777,216 B
    unsigned short* Z       = (unsigned short*)(ws + 58720256);         //  50,331,648 B
    unsigned short* Qb      = (unsigned short*)(ws + 109051904);        //  33,554,432 B
    unsigned short* Kv      = (unsigned short*)(ws + 142606336);        //   8,388,608 B
    unsigned short* Vt      = (unsigned short*)(ws + 150994944);        //   8,388,608 B
    unsigned short* Ob      = (unsigned short*)(ws + 159383552);        //  33,554,432 B
    // total: 192,937,984 B

    {   // casts
        int n4 = (2 * 2048 * 2048) / 4;
        cast_f32_bf16<<<(n4 + 255) / 256, 256, 0, stream>>>(u, u_bf, n4);
        n4 = (6144 * 2048) / 4;   // only the used rows [4096,10240) of W_in
        cast_f32_bf16<<<(n4 + 255) / 256, 256, 0, stream>>>(W_in + (size_t)4096 * 2048, win_bf, n4);
        n4 = (2048 * 4096) / 4;
        cast_f32_bf16<<<(n4 + 255) / 256, 256, 0, stream>>>(W_out, wout_bf, n4);
    }
    {   // GEMM1: Z[4096,6144] = u_bf[4096,2048] @ win_bf[6144,2048]^T  (256^2 8-phase)
        dim3 g(6144 / 256, 4096 / 256);   // 24 x 16 = 384 blocks
        gemm256_bt<<<g, 512, 0, stream>>>(u_bf, win_bf, Z, 4096, 6144, 2048);
    }
    {   // RoPE + split (V stored s-within-64 pair-permuted)
        int n = BATCH * S_LEN * 3584;
        rope_split<<<(n + 255) / 256, 256, 0, stream>>>(Z, Qb, Kv, Vt);
    }
    // attention: grid = (S/64) * B * NH, heavy q-tiles first
    attn_kernel<<<BATCH * NH * (S_LEN / 64), 256, 0, stream>>>(Qb, Kv, Vt, Ob);
    {   // GEMM2: out[4096,2048] = Ob[4096,4096] @ wout_bf[2048,4096]^T  (fp32 store)
        dim3 g(2048 / 128, 4096 / 128);
        gemm_bt<0><<<g, 256, 0, stream>>>(Ob, wout_bf, out, 4096, 2048, 4096);
    }
}

// Round 4
// 530.841 us; speedup vs baseline: 1.0553x; 1.0308x over previous
//
#include <hip/hip_runtime.h>
#include <stdint.h>

#define S_LEN 2048
#define BATCH 2
#define NH 32
#define NKV 8
#define HD 128
#define NE 6144   // extracted columns of zxbcdt: x(1024) | B(1024) | C(4096)

typedef __attribute__((ext_vector_type(8))) short short8;
typedef __attribute__((ext_vector_type(4))) float floatx4;

__device__ __forceinline__ unsigned short f2bf(float f) {
    union { float f; uint32_t u; } v; v.f = f;
    uint32_t u = v.u;
    u += 0x7FFFu + ((u >> 16) & 1u);   // RTN-even (inputs are finite)
    return (unsigned short)(u >> 16);
}
__device__ __forceinline__ float bf2f(unsigned short h) {
    union { uint32_t u; float f; } v; v.u = ((uint32_t)h) << 16;
    return v.f;
}
__device__ __forceinline__ uint32_t cvt_pk_bf16(float lo, float hi) {
    uint32_t r;
    asm("v_cvt_pk_bf16_f32 %0, %1, %2" : "=v"(r) : "v"(lo), "v"(hi));
    return r;
}

// ---------------- cast fp32 -> bf16, 4 elems/thread ----------------
__global__ void cast_f32_bf16(const float* __restrict__ in,
                              unsigned short* __restrict__ out, int n4) {
    int i = blockIdx.x * blockDim.x + threadIdx.x;
    if (i >= n4) return;
    float4 f = reinterpret_cast<const float4*>(in)[i];
    ushort4 o;
    o.x = f2bf(f.x); o.y = f2bf(f.y); o.z = f2bf(f.z); o.w = f2bf(f.w);
    reinterpret_cast<ushort4*>(out)[i] = o;
}

// ---------------- m97-style B^T GEMM (kept for GEMM2): C[M,N] = A*Bt^T ----------------
template <int OUT_BF16>
__global__ void __launch_bounds__(256)
gemm_bt(const unsigned short* __restrict__ A, const unsigned short* __restrict__ Bt,
        void* __restrict__ Cv, int M, int N, int K) {
    __shared__ unsigned short As[128 * 32];
    __shared__ unsigned short Bs[128 * 32];
    const int tid  = threadIdx.x;
    const int w    = tid >> 6;
    const int lane = tid & 63;
    const int quad = lane >> 4;
    const int l16  = lane & 15;
    const int wm   = w >> 1, wn = w & 1;
    const int m0 = blockIdx.y * 128, n0 = blockIdx.x * 128;

    floatx4 acc[4][4];
#pragma unroll
    for (int i = 0; i < 4; i++)
#pragma unroll
        for (int j = 0; j < 4; j++) acc[i][j] = {0.f, 0.f, 0.f, 0.f};

    const int lr = lane >> 2;        // row within 16-row chunk
    const int lk = (lane & 3) * 8;   // k-elem offset within 32
    const int KT = K >> 5;

    for (int kt = 0; kt < KT; ++kt) {
        const int k0 = kt << 5;
        __syncthreads();
#pragma unroll
        for (int c = 0; c < 2; ++c) {
            const int chunk = w * 2 + c;  // wave-uniform
            const unsigned short* ga = A  + (size_t)(m0 + chunk * 16 + lr) * K + k0 + lk;
            __builtin_amdgcn_global_load_lds(
                (const __attribute__((address_space(1))) void*)ga,
                (__attribute__((address_space(3))) void*)(As + chunk * 512), 16, 0, 0);
            const unsigned short* gb = Bt + (size_t)(n0 + chunk * 16 + lr) * K + k0 + lk;
            __builtin_amdgcn_global_load_lds(
                (const __attribute__((address_space(1))) void*)gb,
                (__attribute__((address_space(3))) void*)(Bs + chunk * 512), 16, 0, 0);
        }
        __syncthreads();
        short8 af[4], bf[4];
#pragma unroll
        for (int t = 0; t < 4; ++t) {
            af[t] = *reinterpret_cast<const short8*>(As + (wm * 64 + t * 16 + l16) * 32 + quad * 8);
            bf[t] = *reinterpret_cast<const short8*>(Bs + (wn * 64 + t * 16 + l16) * 32 + quad * 8);
        }
#pragma unroll
        for (int i = 0; i < 4; i++)
#pragma unroll
            for (int j = 0; j < 4; j++)
                acc[i][j] = __builtin_amdgcn_mfma_f32_16x16x32_bf16(af[i], bf[j], acc[i][j], 0, 0, 0);
    }

#pragma unroll
    for (int i = 0; i < 4; i++)
#pragma unroll
        for (int j = 0; j < 4; j++) {
            const int row = m0 + wm * 64 + i * 16 + quad * 4;
            const int col = n0 + wn * 64 + j * 16 + l16;
#pragma unroll
            for (int r = 0; r < 4; r++) {
                float vv = acc[i][j][r];
                if (OUT_BF16)
                    ((unsigned short*)Cv)[(size_t)(row + r) * N + col] = f2bf(vv);
                else
                    ((float*)Cv)[(size_t)(row + r) * N + col] = vv;
            }
        }
}

// ---------------- 256x256 8-phase GEMM (T2+T3+T4+T5), bf16 out ----------------
// C[M,N] = A[M,K] * Bt[N,K]^T. 512 threads = 8 waves (2M x 4N), BK=64,
// 2 K-tile LDS buffers (128 KB -> 1 block/CU). Per K-tile, 4 phases:
//  ph1: ds_read A-half0(8)+B-half0(4) -> 16 MFMA quad(0,0)
//  ph2: ds_read A-half1(8)+B-half1(4) -> quad(1,0)      [all buf reads done]
//  ph3: stage tile t+2 A-halves (4 gload_lds)           -> quad(1,1)
//  ph4: stage tile t+2 B-halves (4 gload_lds)           -> quad(0,1)
// vmcnt(8) once per K-tile (next tile's 8 loads stay in flight), raw
// s_barrier (no __syncthreads vmcnt-drain).
// T2 swizzle, FULL 3-bit (R3 fix): rows are 128B so only a row&7 XOR on the
// 16B-chunk index makes each 8-lane issue group cover all 8 chunks = 32 banks.
// LDS stays linear for gload_lds; global SOURCE col pre-swizzled (rule #21):
// src c8 = (l&7) ^ ((l>>3)&7)  (valid for all 4 row-offsets: 0/8/128/136 == 0 mod 8);
// ds_read applies the same XOR: c8 = k8 ^ (row&7).
__device__ __forceinline__ short8 ldfrag256(const unsigned short* base, int row, int k8) {
    const int c8 = k8 ^ (row & 7);
    return *reinterpret_cast<const short8*>(base + row * 64 + c8 * 8);
}

__global__ void __launch_bounds__(512, 2)
gemm256_bt(const unsigned short* __restrict__ A, const unsigned short* __restrict__ Bt,
           unsigned short* __restrict__ C, int M, int N, int K) {
    __shared__ unsigned short As[2][256 * 64];   // 64 KB
    __shared__ unsigned short Bs[2][256 * 64];   // 64 KB
    const int tid  = threadIdx.x;
    const int w    = tid >> 6;
    const int lane = tid & 63;
    const int quad = lane >> 4;
    const int l16  = lane & 15;
    const int wm   = w >> 2, wn = w & 3;

    // bijective XCD swizzle (nwg % 8 == 0 for our grids)
    const int nwg = gridDim.x * gridDim.y;
    const int cpx = nwg >> 3;
    const int lin = blockIdx.y * gridDim.x + blockIdx.x;
    const int swz = (lin & 7) * cpx + (lin >> 3);
    const int ntx = N >> 8;
    const int m0 = (swz / ntx) << 8;
    const int n0 = (swz % ntx) << 8;

    floatx4 acc[8][4];
#pragma unroll
    for (int i = 0; i < 8; i++)
#pragma unroll
        for (int j = 0; j < 4; j++) acc[i][j] = {0.f, 0.f, 0.f, 0.f};

    // staging: each wave stages rows {w*16 + off + (lane>>3)}, off in {0,8,128,136}.
    // source col8 pre-swizzled to invert the linear-LDS write (rule #21):
    const int l8  = lane >> 3;
    const int c8s = (lane & 7) ^ ((lane >> 3) & 7);
    const unsigned short* apA = A  + (size_t)(m0 + w * 16 + l8) * K + c8s * 8;
    const unsigned short* apB = Bt + (size_t)(n0 + w * 16 + l8) * K + c8s * 8;

#define GLD256(src, dst) __builtin_amdgcn_global_load_lds(                     \
    (const __attribute__((address_space(1))) void*)(src),                      \
    (__attribute__((address_space(3))) void*)(dst), 16, 0, 0)

#define STAGE_A256(bufi, t) do {                                               \
    unsigned short* d = &As[bufi][w * 16 * 64];                                \
    const unsigned short* s = apA + (size_t)(t) * 64;                          \
    GLD256(s,                    d);                                           \
    GLD256(s + (size_t)8 * K,    d + 8 * 64);                                  \
    GLD256(s + (size_t)128 * K,  d + 128 * 64);                                \
    GLD256(s + (size_t)136 * K,  d + 136 * 64);                                \
} while (0)

#define STAGE_B256(bufi, t) do {                                               \
    unsigned short* d = &Bs[bufi][w * 16 * 64];                                \
    const unsigned short* s = apB + (size_t)(t) * 64;                          \
    GLD256(s,                    d);                                           \
    GLD256(s + (size_t)8 * K,    d + 8 * 64);                                  \
    GLD256(s + (size_t)128 * K,  d + 128 * 64);                                \
    GLD256(s + (size_t)136 * K,  d + 136 * 64);                                \
} while (0)

    // prologue: stage tiles 0 and 1
    STAGE_A256(0, 0); STAGE_B256(0, 0);
    STAGE_A256(1, 1); STAGE_B256(1, 1);

    short8 a0[8], a1[8], b0[4], b1[4];
    const int NT = K >> 6;

#pragma unroll 1
    for (int t = 0; t < NT; ++t) {
        const int buf = t & 1;
        const unsigned short* Ab = &As[buf][0];
        const unsigned short* Bb = &Bs[buf][0];

        // top wait: own loads for tile t complete (tile t+1's 8 may stay in flight)
        if (t < NT - 1) { asm volatile("s_waitcnt vmcnt(8)" ::: "memory"); }
        else            { asm volatile("s_waitcnt vmcnt(0)" ::: "memory"); }
        __builtin_amdgcn_s_barrier();     // all waves' tile-t loads landed
        asm volatile("" ::: "memory");

        // ---- ph1: A-half0 + B-half0 ----
#pragma unroll
        for (int mi = 0; mi < 4; ++mi) {
            const int row = wm * 128 + mi * 16 + l16;
            a0[mi * 2 + 0] = ldfrag256(Ab, row, quad);
            a0[mi * 2 + 1] = ldfrag256(Ab, row, 4 + quad);
        }
#pragma unroll
        for (int ni = 0; ni < 2; ++ni) {
            const int row = wn * 64 + ni * 16 + l16;
            b0[ni * 2 + 0] = ldfrag256(Bb, row, quad);
            b0[ni * 2 + 1] = ldfrag256(Bb, row, 4 + quad);
        }
        asm volatile("" ::: "memory");
        __builtin_amdgcn_s_barrier();
        __builtin_amdgcn_s_setprio(1);
#pragma unroll
        for (int mi = 0; mi < 4; ++mi)
#pragma unroll
            for (int ni = 0; ni < 2; ++ni) {
                acc[mi][ni] = __builtin_amdgcn_mfma_f32_16x16x32_bf16(a0[mi*2+0], b0[ni*2+0], acc[mi][ni], 0, 0, 0);
                acc[mi][ni] = __builtin_amdgcn_mfma_f32_16x16x32_bf16(a0[mi*2+1], b0[ni*2+1], acc[mi][ni], 0, 0, 0);
            }
        __builtin_amdgcn_s_setprio(0);
        asm volatile("" ::: "memory");
        __builtin_amdgcn_s_barrier();

        // ---- ph2: A-half1 + B-half1 ----
#pragma unroll
        for (int mi = 0; mi < 4; ++mi) {
            const int row = wm * 128 + 64 + mi * 16 + l16;
            a1[mi * 2 + 0] = ldfrag256(Ab, row, quad);
            a1[mi * 2 + 1] = ldfrag256(Ab, row, 4 + quad);
        }
#pragma unroll
        for (int ni = 0; ni < 2; ++ni) {
            const int row = wn * 64 + 32 + ni * 16 + l16;
            b1[ni * 2 + 0] = ldfrag256(Bb, row, quad);
            b1[ni * 2 + 1] = ldfrag256(Bb, row, 4 + quad);
        }
        asm volatile("" ::: "memory");
        __builtin_amdgcn_s_barrier();
        __builtin_amdgcn_s_setprio(1);
#pragma unroll
        for (int mi = 0; mi < 4; ++mi)
#pragma unroll
            for (int ni = 0; ni < 2; ++ni) {
                acc[4 + mi][ni] = __builtin_amdgcn_mfma_f32_16x16x32_bf16(a1[mi*2+0], b0[ni*2+0], acc[4+mi][ni], 0, 0, 0);
                acc[4 + mi][ni] = __builtin_amdgcn_mfma_f32_16x16x32_bf16(a1[mi*2+1], b0[ni*2+1], acc[4+mi][ni], 0, 0, 0);
            }
        __builtin_amdgcn_s_setprio(0);
        asm volatile("" ::: "memory");
        __builtin_amdgcn_s_barrier();     // all buf reads complete block-wide

        // ---- ph3: stage next-next A + quad(1,1) ----
        if (t + 2 < NT) { STAGE_A256(buf, t + 2); }
        asm volatile("" ::: "memory");
        __builtin_amdgcn_s_barrier();
        __builtin_amdgcn_s_setprio(1);
#pragma unroll
        for (int mi = 0; mi < 4; ++mi)
#pragma unroll
            for (int ni = 0; ni < 2; ++ni) {
                acc[4 + mi][2 + ni] = __builtin_amdgcn_mfma_f32_16x16x32_bf16(a1[mi*2+0], b1[ni*2+0], acc[4+mi][2+ni], 0, 0, 0);
                acc[4 + mi][2 + ni] = __builtin_amdgcn_mfma_f32_16x16x32_bf16(a1[mi*2+1], b1[ni*2+1], acc[4+mi][2+ni], 0, 0, 0);
            }
        __builtin_amdgcn_s_setprio(0);
        asm volatile("" ::: "memory");
        __builtin_amdgcn_s_barrier();     // b1 reads consumed; B-region safe

        // ---- ph4: stage next-next B + quad(0,1) ----
        if (t + 2 < NT) { STAGE_B256(buf, t + 2); }
        asm volatile("" ::: "memory");
        __builtin_amdgcn_s_setprio(1);
#pragma unroll
        for (int mi = 0; mi < 4; ++mi)
#pragma unroll
            for (int ni = 0; ni < 2; ++ni) {
                acc[mi][2 + ni] = __builtin_amdgcn_mfma_f32_16x16x32_bf16(a0[mi*2+0], b1[ni*2+0], acc[mi][2+ni], 0, 0, 0);
                acc[mi][2 + ni] = __builtin_amdgcn_mfma_f32_16x16x32_bf16(a0[mi*2+1], b1[ni*2+1], acc[mi][2+ni], 0, 0, 0);
            }
        __builtin_amdgcn_s_setprio(0);
        // no trailing barrier: next iteration's top vmcnt+barrier covers it
    }
#undef STAGE_A256
#undef STAGE_B256
#undef GLD256

    // ---- epilogue: bf16 store ----
#pragma unroll
    for (int mi = 0; mi < 8; ++mi)
#pragma unroll
        for (int ni = 0; ni < 4; ++ni) {
            const int row = m0 + wm * 128 + mi * 16 + quad * 4;
            const int col = n0 + wn * 64 + ni * 16 + l16;
#pragma unroll
            for (int r = 0; r < 4; ++r)
                C[(size_t)(row + r) * N + col] = f2bf(acc[mi][ni][r]);
        }
}

// ---------------- RoPE + split/reshape ----------------
// Z: [4096 tokens][6144] bf16. Q[B,NH,S,HD] (pre-scaled by log2e/sqrt(128)),
// K[B,NKV,S,HD], Vt[B,NKV,HD,S] with s-within-64 PERMUTED to pair order
// (matches attn's pair-packed P layout; P,V contracted over same permuted k).
#define QSCALE 0.12748539509360f   // log2(e) / sqrt(128)
__global__ void rope_split(const unsigned short* __restrict__ Z,
                           unsigned short* __restrict__ Q,
                           unsigned short* __restrict__ Kb,
                           unsigned short* __restrict__ Vt) {
    const int PER_TOK = 2048 + 512 + 1024;  // q-pairs + k-pairs + v-elems
    int idx = blockIdx.x * blockDim.x + threadIdx.x;
    if (idx >= BATCH * S_LEN * PER_TOK) return;
    int t = idx / PER_TOK;
    int r = idx - t * PER_TOK;
    int b = t / S_LEN, s = t - b * S_LEN;
    const unsigned short* z = Z + (size_t)t * NE;
    if (r < 2048) {                 // q pair: C section
        int h = r >> 6, j = r & 63;
        float x0 = bf2f(z[2048 + h * 128 + j]);
        float x1 = bf2f(z[2048 + h * 128 + j + 64]);
        float inv = exp2f((float)j * -0.20762050593f);   // 10000^(-j/64)
        float c, sn; sincosf((float)s * inv, &sn, &c);
        size_t base = ((size_t)(b * NH + h) * S_LEN + s) * HD;
        Q[base + j]      = f2bf((x0 * c - x1 * sn) * QSCALE);
        Q[base + j + 64] = f2bf((x1 * c + x0 * sn) * QSCALE);
    } else if (r < 2560) {          // k pair: B section
        int rr = r - 2048; int kh = rr >> 6, j = rr & 63;
        float x0 = bf2f(z[1024 + kh * 128 + j]);
        float x1 = bf2f(z[1024 + kh * 128 + j + 64]);
        float inv = exp2f((float)j * -0.20762050593f);
        float c, sn; sincosf((float)s * inv, &sn, &c);
        size_t base = ((size_t)(b * NKV + kh) * S_LEN + s) * HD;
        Kb[base + j]      = f2bf(x0 * c - x1 * sn);
        Kb[base + j + 64] = f2bf(x1 * c + x0 * sn);
    } else {                        // v elem: x section, transposed+permuted store
        int m = r - 2560; int kh = m >> 7, d = m & 127;
        int k = s & 63;
        int kp = (k & 32) + ((k & 15) << 1) + ((k >> 4) & 1);
        int sp = (s & ~63) | kp;
        Vt[((size_t)(b * NKV + kh) * HD + d) * S_LEN + sp] = z[m];
    }
}

// ---------------- Flash attention v2 (causal, GQA 4:1) ----------------
// (unchanged: single-buffered LDS, 4 blocks/CU, pair-packed P via cvt_pk,
// diagonal-tile split, setprio around MFMA.)
template <bool DIAG>
__device__ __forceinline__ void attn_tile(
    const short8 (&qf)[4], floatx4 (&oacc)[8], float (&lsum)[4],
    const unsigned short* __restrict__ Ks, const unsigned short* __restrict__ Vs,
    unsigned short* __restrict__ pw, int w, int quad, int l16) {
    const int e = l16 & 7;

    // ---- QK^T: 4 n-tiles x 4 k-chunks ----
    floatx4 sacc[4];
#pragma unroll
    for (int nb = 0; nb < 4; nb++) sacc[nb] = {0.f, 0.f, 0.f, 0.f};
    __builtin_amdgcn_s_setprio(1);
#pragma unroll
    for (int ks = 0; ks < 4; ++ks) {
#pragma unroll
        for (int nb = 0; nb < 4; ++nb) {
            const int srow = nb * 16 + l16;
            const int pc = (ks * 4 + quad) ^ e;
            short8 kf = *reinterpret_cast<const short8*>(Ks + srow * 128 + pc * 8);
            sacc[nb] = __builtin_amdgcn_mfma_f32_16x16x32_bf16(qf[ks], kf, sacc[nb], 0, 0, 0);
        }
    }
    __builtin_amdgcn_s_setprio(0);

    // ---- exp2 (+ causal mask only on diagonal tile) ----
    float pv[4][4];
#pragma unroll
    for (int nb = 0; nb < 4; ++nb)
#pragma unroll
        for (int r = 0; r < 4; ++r) {
            float p = exp2f(sacc[nb][r]);
            if (DIAG)
                p = (nb * 16 + l16 <= w * 16 + quad * 4 + r) ? p : 0.0f;
            pv[nb][r] = p;
            lsum[r] += p;
        }

    // ---- P store: pair-packed b32, XOR chunk swizzle (2-way, free) ----
    const int row0 = quad * 4;
    const int sub = l16 >> 2, off = (l16 & 3) * 2;
#pragma unroll
    for (int r = 0; r < 4; ++r) {
        const int rowe = (row0 + r) & 7;
#pragma unroll
        for (int g = 0; g < 2; ++g) {
            uint32_t pk = cvt_pk_bf16(pv[g * 2][r], pv[g * 2 + 1][r]);
            const int chunk = (g * 4 + sub) ^ rowe;
            *reinterpret_cast<uint32_t*>(pw + (row0 + r) * 64 + chunk * 8 + off) = pk;
        }
    }

    // ---- PV: 2 k-chunks x 8 d-tiles (wave-private Ps, no barrier) ----
    __builtin_amdgcn_s_setprio(1);
#pragma unroll
    for (int kv_sub = 0; kv_sub < 2; ++kv_sub) {
        const int pcP = (kv_sub * 4 + quad) ^ e;
        short8 pf = *reinterpret_cast<const short8*>(pw + l16 * 64 + pcP * 8);
#pragma unroll
        for (int dt = 0; dt < 8; ++dt) {
            const int drow = dt * 16 + l16;
            const int pcV = (kv_sub * 4 + quad) ^ e;
            short8 vf = *reinterpret_cast<const short8*>(Vs + drow * 64 + pcV * 8);
            oacc[dt] = __builtin_amdgcn_mfma_f32_16x16x32_bf16(pf, vf, oacc[dt], 0, 0, 0);
        }
    }
    __builtin_amdgcn_s_setprio(0);
}

__global__ void __launch_bounds__(256, 4)
attn_kernel(const unsigned short* __restrict__ Q,
            const unsigned short* __restrict__ Kb,
            const unsigned short* __restrict__ Vt,
            unsigned short* __restrict__ Ob) {
    __shared__ unsigned short Ks[64 * 128];   // [s][d] swizzled, 16 KB
    __shared__ unsigned short Vs[128 * 64];   // [d][s'] swizzled, 16 KB
    __shared__ unsigned short Ps[4][16 * 64]; // per-wave P, swizzled, 8 KB
    const int tid  = threadIdx.x;
    const int w    = tid >> 6;
    const int lane = tid & 63;
    const int quad = lane >> 4;
    const int l16  = lane & 15;
    const int blk = blockIdx.x;
    const int qt = 31 - (blk >> 6);      // heavy blocks dispatch first
    const int bh = blk & 63;
    const int h = bh & 31, b = bh >> 5;
    const int kvh = h >> 2;
    const int qw0 = qt * 64 + w * 16;

    const unsigned short* Qbase = Q  + ((size_t)(b * NH  + h)   * S_LEN) * HD;
    const unsigned short* Kbase = Kb + ((size_t)(b * NKV + kvh) * S_LEN) * HD;
    const unsigned short* Vbase = Vt + ((size_t)(b * NKV + kvh) * HD) * S_LEN;

    short8 qf[4];
    {
        const unsigned short* qrow = Qbase + (size_t)(qw0 + l16) * HD + quad * 8;
#pragma unroll
        for (int ks = 0; ks < 4; ++ks)
            qf[ks] = *reinterpret_cast<const short8*>(qrow + ks * 32);
    }

    floatx4 oacc[8];
#pragma unroll
    for (int i = 0; i < 8; i++) oacc[i] = {0.f, 0.f, 0.f, 0.f};
    float lsum[4] = {0.f, 0.f, 0.f, 0.f};

    // per-lane staging pointers, advanced one KV tile per STAGE
    const unsigned short* kp[4];
    const unsigned short* vp[4];
#pragma unroll
    for (int c = 0; c < 4; ++c) {
        const int bI = w * 4 + c;                       // wave-uniform block idx
        const int krow = bI * 4 + (lane >> 4);          // 0..63
        kp[c] = Kbase + (size_t)krow * HD + ((lane & 15) ^ (krow & 7)) * 8;
        const int drow = bI * 8 + (lane >> 3);          // 0..127
        vp[c] = Vbase + (size_t)drow * S_LEN + ((lane & 7) ^ (drow & 7)) * 8;
    }

#define STAGE() do {                                                           \
    _Pragma("unroll")                                                          \
    for (int c = 0; c < 4; ++c) {                                              \
        const int bI = w * 4 + c;                                              \
        __builtin_amdgcn_global_load_lds(                                      \
            (const __attribute__((address_space(1))) void*)kp[c],              \
            (__attribute__((address_space(3))) void*)(Ks + bI * 512), 16, 0, 0);\
        __builtin_amdgcn_global_load_lds(                                      \
            (const __attribute__((address_space(1))) void*)vp[c],              \
            (__attribute__((address_space(3))) void*)(Vs + bI * 512), 16, 0, 0);\
        kp[c] += 64 * HD; vp[c] += 64;                                         \
    }                                                                          \
} while (0)

    unsigned short* pw = &Ps[w][0];

    // main loop: tiles strictly below the diagonal block -> no masking
    for (int t = 0; t < qt; ++t) {
        __syncthreads();   // previous-iter LDS reads done before overwrite
        STAGE();
        __syncthreads();   // staging complete
        attn_tile<false>(qf, oacc, lsum, Ks, Vs, pw, w, quad, l16);
    }
    // diagonal tile: masked
    __syncthreads();
    STAGE();
    __syncthreads();
    attn_tile<true>(qf, oacc, lsum, Ks, Vs, pw, w, quad, l16);
#undef STAGE

    // ---- final row-sum reduce + write ----
    float linv[4];
#pragma unroll
    for (int r = 0; r < 4; ++r) {
        float s = lsum[r];
#pragma unroll
        for (int off = 1; off < 16; off <<= 1) s += __shfl_xor(s, off);
        linv[r] = 1.0f / s;
    }
#pragma unroll
    for (int dt = 0; dt < 8; ++dt) {
        const int d = dt * 16 + l16;
#pragma unroll
        for (int r = 0; r < 4; ++r) {
            const int row = qw0 + quad * 4 + r;
            Ob[((size_t)(b * S_LEN + row)) * 4096 + h * 128 + d] = f2bf(oacc[dt][r] * linv[r]);
        }
    }
}

extern "C" void kernel_launch(void* const* d_in, const int* in_sizes, int n_in,
                              void* d_out, int out_size, void* d_ws, size_t ws_size,
                              hipStream_t stream) {
    const float* u     = (const float*)d_in[0];
    const float* W_in  = (const float*)d_in[1];
    const float* W_out = (const float*)d_in[2];
    float* out = (float*)d_out;

    char* ws = (char*)d_ws;
    unsigned short* u_bf    = (unsigned short*)(ws);                    //  16,777,216 B
    unsigned short* win_bf  = (unsigned short*)(ws + 16777216);         //  25,165,824 B
    unsigned short* wout_bf = (unsigned short*)(ws + 41943040);         //  16,777,216 B
    unsigned short* Z       = (unsigned short*)(ws + 58720256);         //  50,331,648 B
    unsigned short* Qb      = (unsigned short*)(ws + 109051904);        //  33,554,432 B
    unsigned short* Kv      = (unsigned short*)(ws + 142606336);        //   8,388,608 B
    unsigned short* Vt      = (unsigned short*)(ws + 150994944);        //   8,388,608 B
    unsigned short* Ob      = (unsigned short*)(ws + 159383552);        //  33,554,432 B
    // total: 192,937,984 B

    {   // casts
        int n4 = (2 * 2048 * 2048) / 4;
        cast_f32_bf16<<<(n4 + 255) / 256, 256, 0, stream>>>(u, u_bf, n4);
        n4 = (6144 * 2048) / 4;   // only the used rows [4096,10240) of W_in
        cast_f32_bf16<<<(n4 + 255) / 256, 256, 0, stream>>>(W_in + (size_t)4096 * 2048, win_bf, n4);
        n4 = (2048 * 4096) / 4;
        cast_f32_bf16<<<(n4 + 255) / 256, 256, 0, stream>>>(W_out, wout_bf, n4);
    }
    {   // GEMM1: Z[4096,6144] = u_bf[4096,2048] @ win_bf[6144,2048]^T  (256^2 8-phase)
        dim3 g(6144 / 256, 4096 / 256);   // 24 x 16 = 384 blocks
        gemm256_bt<<<g, 512, 0, stream>>>(u_bf, win_bf, Z, 4096, 6144, 2048);
    }
    {   // RoPE + split (V stored s-within-64 pair-permuted)
        int n = BATCH * S_LEN * 3584;
        rope_split<<<(n + 255) / 256, 256, 0, stream>>>(Z, Qb, Kv, Vt);
    }
    // attention: grid = (S/64) * B * NH, heavy q-tiles first
    attn_kernel<<<BATCH * NH * (S_LEN / 64), 256, 0, stream>>>(Qb, Kv, Vt, Ob);
    {   // GEMM2: out[4096,2048] = Ob[4096,4096] @ wout_bf[2048,4096]^T  (fp32 store)
        dim3 g(2048 / 128, 4096 / 128);
        gemm_bt<0><<<g, 256, 0, stream>>>(Ob, wout_bf, out, 4096, 2048, 4096);
    }
}

// Round 5
// 494.241 us; speedup vs baseline: 1.1335x; 1.0741x over previous
//
#include <hip/hip_runtime.h>
#include <stdint.h>

#define S_LEN 2048
#define BATCH 2
#define NH 32
#define NKV 8
#define HD 128
#define NE 6144   // extracted columns of zxbcdt: x(1024) | B(1024) | C(4096)

typedef __attribute__((ext_vector_type(8))) short short8;
typedef __attribute__((ext_vector_type(4))) float floatx4;

__device__ __forceinline__ unsigned short f2bf(float f) {
    union { float f; uint32_t u; } v; v.f = f;
    uint32_t u = v.u;
    u += 0x7FFFu + ((u >> 16) & 1u);   // RTN-even (inputs are finite)
    return (unsigned short)(u >> 16);
}
__device__ __forceinline__ float bf2f(unsigned short h) {
    union { uint32_t u; float f; } v; v.u = ((uint32_t)h) << 16;
    return v.f;
}
__device__ __forceinline__ uint32_t cvt_pk_bf16(float lo, float hi) {
    uint32_t r;
    asm("v_cvt_pk_bf16_f32 %0, %1, %2" : "=v"(r) : "v"(lo), "v"(hi));
    return r;
}

// ---------------- cast fp32 -> bf16, 4 elems/thread ----------------
__global__ void cast_f32_bf16(const float* __restrict__ in,
                              unsigned short* __restrict__ out, int n4) {
    int i = blockIdx.x * blockDim.x + threadIdx.x;
    if (i >= n4) return;
    float4 f = reinterpret_cast<const float4*>(in)[i];
    ushort4 o;
    o.x = f2bf(f.x); o.y = f2bf(f.y); o.z = f2bf(f.z); o.w = f2bf(f.w);
    reinterpret_cast<ushort4*>(out)[i] = o;
}

// ---------------- 256x128 2-phase/K-tile GEMM engine (T2+T3+T4+T5) ----------------
// C[M,N] = A[M,K] * Bt[N,K]^T. 512 threads = 8 waves (4M x 2N), per-wave 64x64,
// BK=64, TRIPLE-buffered LDS (A 3x32KB + B 3x16KB = 144 KB, 1 block/CU).
// Grids chosen for EXACT rounds: GEMM1 768 blocks (3 rounds), GEMM2 256 (1 round).
// Per K-tile: 2 phases, each { 8 ds_read + 3 global_load_lds interleaved;
// barrier; 16 MFMA (setprio) ; barrier } -- fine interleave per m196/m201.
// vmcnt(6) counted once per tile (next tile's 6 loads stay in flight).
// 3 buffers kill the read-vs-overwrite hazard: tile t+2 -> buf (t+2)%3 holds
// tile t-1, whose reads were lgkm-drained before each wave's ph2 MFMA of
// iter t-1, published block-wide by this iter's top barrier.
// T2 swizzle (R4-verified): LDS linear for gload_lds; global SOURCE chunk
// pre-swizzled c8s = (l&7)^((l>>3)&7); ds_read XORs back: c8 = k8 ^ (row&7).
__device__ __forceinline__ short8 ldfragg(const unsigned short* base, int row, int k8) {
    const int c8 = k8 ^ (row & 7);
    return *reinterpret_cast<const short8*>(base + row * 64 + c8 * 8);
}

template <int OUT_BF16>
__global__ void __launch_bounds__(512, 2)
gemm_256x128(const unsigned short* __restrict__ A, const unsigned short* __restrict__ Bt,
             void* __restrict__ Cv, int M, int N, int K) {
    __shared__ unsigned short As[3][256 * 64];   // 96 KB
    __shared__ unsigned short Bs[3][128 * 64];   // 48 KB
    const int tid  = threadIdx.x;
    const int w    = tid >> 6;
    const int lane = tid & 63;
    const int quad = lane >> 4;
    const int l16  = lane & 15;
    const int wm   = w >> 1, wn = w & 1;     // 4M x 2N wave grid

    // bijective XCD swizzle (nwg % 8 == 0 for our grids)
    const int nwg = gridDim.x * gridDim.y;
    const int cpx = nwg >> 3;
    const int lin = blockIdx.y * gridDim.x + blockIdx.x;
    const int swz = (lin & 7) * cpx + (lin >> 3);
    const int ntx = N >> 7;
    const int m0 = (swz / ntx) << 8;
    const int n0 = (swz % ntx) << 7;

    floatx4 acc[4][4];
#pragma unroll
    for (int i = 0; i < 4; i++)
#pragma unroll
        for (int j = 0; j < 4; j++) acc[i][j] = {0.f, 0.f, 0.f, 0.f};

    // staging addresses: wave w owns A rows [w*32, w*32+32) (4 loads) and
    // B rows [w*16, w*16+16) (2 loads); each gload_lds covers 8 rows.
    const int l8  = lane >> 3;
    const int c8s = (lane & 7) ^ ((lane >> 3) & 7);   // inverse swizzle on source
    const unsigned short* apA = A  + (size_t)(m0 + w * 32 + l8) * K + c8s * 8;
    const unsigned short* apB = Bt + (size_t)(n0 + w * 16 + l8) * K + c8s * 8;

#define GLD(src, dst) __builtin_amdgcn_global_load_lds(                        \
    (const __attribute__((address_space(1))) void*)(src),                      \
    (__attribute__((address_space(3))) void*)(dst), 16, 0, 0)

#define STG1(bufi, t) do {              /* A rows +0,+8,+16 : 3 loads */       \
    unsigned short* d = &As[bufi][w * 32 * 64];                                \
    const unsigned short* s = apA + (size_t)(t) * 64;                          \
    GLD(s,                   d);                                               \
    GLD(s + (size_t)8  * K,  d + 8  * 64);                                     \
    GLD(s + (size_t)16 * K,  d + 16 * 64);                                     \
} while (0)

#define STG2(bufi, t) do {              /* A row +24, B rows +0,+8 : 3 loads */\
    unsigned short* dA = &As[bufi][w * 32 * 64];                               \
    const unsigned short* sA = apA + (size_t)(t) * 64;                         \
    GLD(sA + (size_t)24 * K, dA + 24 * 64);                                    \
    unsigned short* dB = &Bs[bufi][w * 16 * 64];                               \
    const unsigned short* sB = apB + (size_t)(t) * 64;                         \
    GLD(sB,                  dB);                                              \
    GLD(sB + (size_t)8 * K,  dB + 8 * 64);                                     \
} while (0)

    // prologue: stage tiles 0 and 1
    STG1(0, 0); STG2(0, 0);
    STG1(1, 1); STG2(1, 1);

    const int NT = K >> 6;
    int bufc = 0;                       // buffer of tile t (t % 3)

#pragma unroll 1
    for (int t = 0; t < NT; ++t) {
        const unsigned short* Ab = &As[bufc][0];
        const unsigned short* Bb = &Bs[bufc][0];
        const int bufn = (bufc + 2 >= 3) ? bufc - 1 : bufc + 2;   // (t+2)%3

        // counted wait: tile t's 6 loads landed; tile t+1's 6 stay in flight
        if (t < NT - 1) { asm volatile("s_waitcnt vmcnt(6)" ::: "memory"); }
        else            { asm volatile("s_waitcnt vmcnt(0)" ::: "memory"); }
        __builtin_amdgcn_s_barrier();
        asm volatile("" ::: "memory");

        // ---- phase 1: k-chunk 0 ----
        short8 a0[4], b0[4];
#pragma unroll
        for (int mi = 0; mi < 4; ++mi)
            a0[mi] = ldfragg(Ab, wm * 64 + mi * 16 + l16, quad);
#pragma unroll
        for (int ni = 0; ni < 4; ++ni)
            b0[ni] = ldfragg(Bb, wn * 64 + ni * 16 + l16, quad);
        if (t + 2 < NT) { STG1(bufn, t + 2); }
        asm volatile("" ::: "memory");
        __builtin_amdgcn_s_barrier();
        __builtin_amdgcn_s_setprio(1);
#pragma unroll
        for (int mi = 0; mi < 4; ++mi)
#pragma unroll
            for (int ni = 0; ni < 4; ++ni)
                acc[mi][ni] = __builtin_amdgcn_mfma_f32_16x16x32_bf16(a0[mi], b0[ni], acc[mi][ni], 0, 0, 0);
        __builtin_amdgcn_s_setprio(0);
        asm volatile("" ::: "memory");
        __builtin_amdgcn_s_barrier();

        // ---- phase 2: k-chunk 1 ----
        short8 a1[4], b1[4];
#pragma unroll
        for (int mi = 0; mi < 4; ++mi)
            a1[mi] = ldfragg(Ab, wm * 64 + mi * 16 + l16, 4 + quad);
#pragma unroll
        for (int ni = 0; ni < 4; ++ni)
            b1[ni] = ldfragg(Bb, wn * 64 + ni * 16 + l16, 4 + quad);
        if (t + 2 < NT) { STG2(bufn, t + 2); }
        asm volatile("" ::: "memory");
        __builtin_amdgcn_s_barrier();
        __builtin_amdgcn_s_setprio(1);
#pragma unroll
        for (int mi = 0; mi < 4; ++mi)
#pragma unroll
            for (int ni = 0; ni < 4; ++ni)
                acc[mi][ni] = __builtin_amdgcn_mfma_f32_16x16x32_bf16(a1[mi], b1[ni], acc[mi][ni], 0, 0, 0);
        __builtin_amdgcn_s_setprio(0);
        // no trailing barrier: next iter's vmcnt+barrier covers publication

        bufc = (bufc + 1 >= 3) ? 0 : bufc + 1;
    }
#undef STG1
#undef STG2
#undef GLD

    // ---- epilogue ----
#pragma unroll
    for (int mi = 0; mi < 4; ++mi)
#pragma unroll
        for (int ni = 0; ni < 4; ++ni) {
            const int row = m0 + wm * 64 + mi * 16 + quad * 4;
            const int col = n0 + wn * 64 + ni * 16 + l16;
#pragma unroll
            for (int r = 0; r < 4; ++r) {
                float vv = acc[mi][ni][r];
                if (OUT_BF16)
                    ((unsigned short*)Cv)[(size_t)(row + r) * N + col] = f2bf(vv);
                else
                    ((float*)Cv)[(size_t)(row + r) * N + col] = vv;
            }
        }
}

// ---------------- RoPE + split/reshape ----------------
// Z: [4096 tokens][6144] bf16. Q[B,NH,S,HD] (pre-scaled by log2e/sqrt(128)),
// K[B,NKV,S,HD], Vt[B,NKV,HD,S] with s-within-64 PERMUTED to pair order
// (matches attn's pair-packed P layout; P,V contracted over same permuted k).
#define QSCALE 0.12748539509360f   // log2(e) / sqrt(128)
__global__ void rope_split(const unsigned short* __restrict__ Z,
                           unsigned short* __restrict__ Q,
                           unsigned short* __restrict__ Kb,
                           unsigned short* __restrict__ Vt) {
    const int PER_TOK = 2048 + 512 + 1024;  // q-pairs + k-pairs + v-elems
    int idx = blockIdx.x * blockDim.x + threadIdx.x;
    if (idx >= BATCH * S_LEN * PER_TOK) return;
    int t = idx / PER_TOK;
    int r = idx - t * PER_TOK;
    int b = t / S_LEN, s = t - b * S_LEN;
    const unsigned short* z = Z + (size_t)t * NE;
    if (r < 2048) {                 // q pair: C section
        int h = r >> 6, j = r & 63;
        float x0 = bf2f(z[2048 + h * 128 + j]);
        float x1 = bf2f(z[2048 + h * 128 + j + 64]);
        float inv = exp2f((float)j * -0.20762050593f);   // 10000^(-j/64)
        float c, sn; sincosf((float)s * inv, &sn, &c);
        size_t base = ((size_t)(b * NH + h) * S_LEN + s) * HD;
        Q[base + j]      = f2bf((x0 * c - x1 * sn) * QSCALE);
        Q[base + j + 64] = f2bf((x1 * c + x0 * sn) * QSCALE);
    } else if (r < 2560) {          // k pair: B section
        int rr = r - 2048; int kh = rr >> 6, j = rr & 63;
        float x0 = bf2f(z[1024 + kh * 128 + j]);
        float x1 = bf2f(z[1024 + kh * 128 + j + 64]);
        float inv = exp2f((float)j * -0.20762050593f);
        float c, sn; sincosf((float)s * inv, &sn, &c);
        size_t base = ((size_t)(b * NKV + kh) * S_LEN + s) * HD;
        Kb[base + j]      = f2bf(x0 * c - x1 * sn);
        Kb[base + j + 64] = f2bf(x1 * c + x0 * sn);
    } else {                        // v elem: x section, transposed+permuted store
        int m = r - 2560; int kh = m >> 7, d = m & 127;
        int k = s & 63;
        int kp = (k & 32) + ((k & 15) << 1) + ((k >> 4) & 1);
        int sp = (s & ~63) | kp;
        Vt[((size_t)(b * NKV + kh) * HD + d) * S_LEN + sp] = z[m];
    }
}

// ---------------- Flash attention v2 (causal, GQA 4:1) ----------------
// (unchanged: single-buffered LDS, 4 blocks/CU, pair-packed P via cvt_pk,
// diagonal-tile split, setprio around MFMA.)
template <bool DIAG>
__device__ __forceinline__ void attn_tile(
    const short8 (&qf)[4], floatx4 (&oacc)[8], float (&lsum)[4],
    const unsigned short* __restrict__ Ks, const unsigned short* __restrict__ Vs,
    unsigned short* __restrict__ pw, int w, int quad, int l16) {
    const int e = l16 & 7;

    // ---- QK^T: 4 n-tiles x 4 k-chunks ----
    floatx4 sacc[4];
#pragma unroll
    for (int nb = 0; nb < 4; nb++) sacc[nb] = {0.f, 0.f, 0.f, 0.f};
    __builtin_amdgcn_s_setprio(1);
#pragma unroll
    for (int ks = 0; ks < 4; ++ks) {
#pragma unroll
        for (int nb = 0; nb < 4; ++nb) {
            const int srow = nb * 16 + l16;
            const int pc = (ks * 4 + quad) ^ e;
            short8 kf = *reinterpret_cast<const short8*>(Ks + srow * 128 + pc * 8);
            sacc[nb] = __builtin_amdgcn_mfma_f32_16x16x32_bf16(qf[ks], kf, sacc[nb], 0, 0, 0);
        }
    }
    __builtin_amdgcn_s_setprio(0);

    // ---- exp2 (+ causal mask only on diagonal tile) ----
    float pv[4][4];
#pragma unroll
    for (int nb = 0; nb < 4; ++nb)
#pragma unroll
        for (int r = 0; r < 4; ++r) {
            float p = exp2f(sacc[nb][r]);
            if (DIAG)
                p = (nb * 16 + l16 <= w * 16 + quad * 4 + r) ? p : 0.0f;
            pv[nb][r] = p;
            lsum[r] += p;
        }

    // ---- P store: pair-packed b32, XOR chunk swizzle (2-way, free) ----
    const int row0 = quad * 4;
    const int sub = l16 >> 2, off = (l16 & 3) * 2;
#pragma unroll
    for (int r = 0; r < 4; ++r) {
        const int rowe = (row0 + r) & 7;
#pragma unroll
        for (int g = 0; g < 2; ++g) {
            uint32_t pk = cvt_pk_bf16(pv[g * 2][r], pv[g * 2 + 1][r]);
            const int chunk = (g * 4 + sub) ^ rowe;
            *reinterpret_cast<uint32_t*>(pw + (row0 + r) * 64 + chunk * 8 + off) = pk;
        }
    }

    // ---- PV: 2 k-chunks x 8 d-tiles (wave-private Ps, no barrier) ----
    __builtin_amdgcn_s_setprio(1);
#pragma unroll
    for (int kv_sub = 0; kv_sub < 2; ++kv_sub) {
        const int pcP = (kv_sub * 4 + quad) ^ e;
        short8 pf = *reinterpret_cast<const short8*>(pw + l16 * 64 + pcP * 8);
#pragma unroll
        for (int dt = 0; dt < 8; ++dt) {
            const int drow = dt * 16 + l16;
            const int pcV = (kv_sub * 4 + quad) ^ e;
            short8 vf = *reinterpret_cast<const short8*>(Vs + drow * 64 + pcV * 8);
            oacc[dt] = __builtin_amdgcn_mfma_f32_16x16x32_bf16(pf, vf, oacc[dt], 0, 0, 0);
        }
    }
    __builtin_amdgcn_s_setprio(0);
}

__global__ void __launch_bounds__(256, 4)
attn_kernel(const unsigned short* __restrict__ Q,
            const unsigned short* __restrict__ Kb,
            const unsigned short* __restrict__ Vt,
            unsigned short* __restrict__ Ob) {
    __shared__ unsigned short Ks[64 * 128];   // [s][d] swizzled, 16 KB
    __shared__ unsigned short Vs[128 * 64];   // [d][s'] swizzled, 16 KB
    __shared__ unsigned short Ps[4][16 * 64]; // per-wave P, swizzled, 8 KB
    const int tid  = threadIdx.x;
    const int w    = tid >> 6;
    const int lane = tid & 63;
    const int quad = lane >> 4;
    const int l16  = lane & 15;
    const int blk = blockIdx.x;
    const int qt = 31 - (blk >> 6);      // heavy blocks dispatch first
    const int bh = blk & 63;
    const int h = bh & 31, b = bh >> 5;
    const int kvh = h >> 2;
    const int qw0 = qt * 64 + w * 16;

    const unsigned short* Qbase = Q  + ((size_t)(b * NH  + h)   * S_LEN) * HD;
    const unsigned short* Kbase = Kb + ((size_t)(b * NKV + kvh) * S_LEN) * HD;
    const unsigned short* Vbase = Vt + ((size_t)(b * NKV + kvh) * HD) * S_LEN;

    short8 qf[4];
    {
        const unsigned short* qrow = Qbase + (size_t)(qw0 + l16) * HD + quad * 8;
#pragma unroll
        for (int ks = 0; ks < 4; ++ks)
            qf[ks] = *reinterpret_cast<const short8*>(qrow + ks * 32);
    }

    floatx4 oacc[8];
#pragma unroll
    for (int i = 0; i < 8; i++) oacc[i] = {0.f, 0.f, 0.f, 0.f};
    float lsum[4] = {0.f, 0.f, 0.f, 0.f};

    // per-lane staging pointers, advanced one KV tile per STAGE
    const unsigned short* kp[4];
    const unsigned short* vp[4];
#pragma unroll
    for (int c = 0; c < 4; ++c) {
        const int bI = w * 4 + c;                       // wave-uniform block idx
        const int krow = bI * 4 + (lane >> 4);          // 0..63
        kp[c] = Kbase + (size_t)krow * HD + ((lane & 15) ^ (krow & 7)) * 8;
        const int drow = bI * 8 + (lane >> 3);          // 0..127
        vp[c] = Vbase + (size_t)drow * S_LEN + ((lane & 7) ^ (drow & 7)) * 8;
    }

#define STAGE() do {                                                           \
    _Pragma("unroll")                                                          \
    for (int c = 0; c < 4; ++c) {                                              \
        const int bI = w * 4 + c;                                              \
        __builtin_amdgcn_global_load_lds(                                      \
            (const __attribute__((address_space(1))) void*)kp[c],              \
            (__attribute__((address_space(3))) void*)(Ks + bI * 512), 16, 0, 0);\
        __builtin_amdgcn_global_load_lds(                                      \
            (const __attribute__((address_space(1))) void*)vp[c],              \
            (__attribute__((address_space(3))) void*)(Vs + bI * 512), 16, 0, 0);\
        kp[c] += 64 * HD; vp[c] += 64;                                         \
    }                                                                          \
} while (0)

    unsigned short* pw = &Ps[w][0];

    // main loop: tiles strictly below the diagonal block -> no masking
    for (int t = 0; t < qt; ++t) {
        __syncthreads();   // previous-iter LDS reads done before overwrite
        STAGE();
        __syncthreads();   // staging complete
        attn_tile<false>(qf, oacc, lsum, Ks, Vs, pw, w, quad, l16);
    }
    // diagonal tile: masked
    __syncthreads();
    STAGE();
    __syncthreads();
    attn_tile<true>(qf, oacc, lsum, Ks, Vs, pw, w, quad, l16);
#undef STAGE

    // ---- final row-sum reduce + write ----
    float linv[4];
#pragma unroll
    for (int r = 0; r < 4; ++r) {
        float s = lsum[r];
#pragma unroll
        for (int off = 1; off < 16; off <<= 1) s += __shfl_xor(s, off);
        linv[r] = 1.0f / s;
    }
#pragma unroll
    for (int dt = 0; dt < 8; ++dt) {
        const int d = dt * 16 + l16;
#pragma unroll
        for (int r = 0; r < 4; ++r) {
            const int row = qw0 + quad * 4 + r;
            Ob[((size_t)(b * S_LEN + row)) * 4096 + h * 128 + d] = f2bf(oacc[dt][r] * linv[r]);
        }
    }
}

extern "C" void kernel_launch(void* const* d_in, const int* in_sizes, int n_in,
                              void* d_out, int out_size, void* d_ws, size_t ws_size,
                              hipStream_t stream) {
    const float* u     = (const float*)d_in[0];
    const float* W_in  = (const float*)d_in[1];
    const float* W_out = (const float*)d_in[2];
    float* out = (float*)d_out;

    char* ws = (char*)d_ws;
    unsigned short* u_bf    = (unsigned short*)(ws);                    //  16,777,216 B
    unsigned short* win_bf  = (unsigned short*)(ws + 16777216);         //  25,165,824 B
    unsigned short* wout_bf = (unsigned short*)(ws + 41943040);         //  16,777,216 B
    unsigned short* Z       = (unsigned short*)(ws + 58720256);         //  50,331,648 B
    unsigned short* Qb      = (unsigned short*)(ws + 109051904);        //  33,554,432 B
    unsigned short* Kv      = (unsigned short*)(ws + 142606336);        //   8,388,608 B
    unsigned short* Vt      = (unsigned short*)(ws + 150994944);        //   8,388,608 B
    unsigned short* Ob      = (unsigned short*)(ws + 159383552);        //  33,554,432 B
    // total: 192,937,984 B

    {   // casts
        int n4 = (2 * 2048 * 2048) / 4;
        cast_f32_bf16<<<(n4 + 255) / 256, 256, 0, stream>>>(u, u_bf, n4);
        n4 = (6144 * 2048) / 4;   // only the used rows [4096,10240) of W_in
        cast_f32_bf16<<<(n4 + 255) / 256, 256, 0, stream>>>(W_in + (size_t)4096 * 2048, win_bf, n4);
        n4 = (2048 * 4096) / 4;
        cast_f32_bf16<<<(n4 + 255) / 256, 256, 0, stream>>>(W_out, wout_bf, n4);
    }
    {   // GEMM1: Z[4096,6144] = u_bf[4096,2048] @ win_bf[6144,2048]^T
        dim3 g(6144 / 128, 4096 / 256);   // 48 x 16 = 768 blocks = 3 exact rounds
        gemm_256x128<1><<<g, 512, 0, stream>>>(u_bf, win_bf, Z, 4096, 6144, 2048);
    }
    {   // RoPE + split (V stored s-within-64 pair-permuted)
        int n = BATCH * S_LEN * 3584;
        rope_split<<<(n + 255) / 256, 256, 0, stream>>>(Z, Qb, Kv, Vt);
    }
    // attention: grid = (S/64) * B * NH, heavy q-tiles first
    attn_kernel<<<BATCH * NH * (S_LEN / 64), 256, 0, stream>>>(Qb, Kv, Vt, Ob);
    {   // GEMM2: out[4096,2048] = Ob[4096,4096] @ wout_bf[2048,4096]^T (fp32 store)
        dim3 g(2048 / 128, 4096 / 256);   // 16 x 16 = 256 blocks = 1 exact round
        gemm_256x128<0><<<g, 512, 0, stream>>>(Ob, wout_bf, out, 4096, 2048, 4096);
    }
}